// Round 13
// baseline (539.573 us; speedup 1.0000x reference)
//
#include <hip/hip_runtime.h>
#include <math.h>

#define T_TOK 16384
#define M_MSG 256
#define L_TOK 64
#define KK 6
#define NQ (M_MSG * KK)   // 1536
#define D_HID 256
#define NH 4
#define HD 64
#define KT 10
#define NBATCH 8

// ---------- helpers ----------
__device__ __forceinline__ unsigned ordf(float f) {
  unsigned u = __float_as_uint(f);
  return (u & 0x80000000u) ? ~u : (u | 0x80000000u);
}
__device__ __forceinline__ float unordf(unsigned u) {
  return __uint_as_float((u & 0x80000000u) ? (u ^ 0x80000000u) : ~u);
}

// ---------- 0. weight k-panel transpose ----------
__global__ __launch_bounds__(64) void wpanel_kernel(
    const float* __restrict__ Wk, const float* __restrict__ Wv,
    const float* __restrict__ Wq, const float* __restrict__ Wo,
    const float* __restrict__ Wi1, float4* __restrict__ WkP,
    float4* __restrict__ WvP, float4* __restrict__ WqP,
    float4* __restrict__ WoP, float4* __restrict__ Wi1P) {
  int c = blockIdx.x;    // 0..255 (column)
  int k4 = threadIdx.x;  // 0..63 (dim group)
  WkP[k4 * 256 + c] = ((const float4*)(Wk + (size_t)c * 256))[k4];
  WvP[k4 * 256 + c] = ((const float4*)(Wv + (size_t)c * 256))[k4];
  WqP[k4 * 256 + c] = ((const float4*)(Wq + (size_t)c * 256))[k4];
  WoP[k4 * 256 + c] = ((const float4*)(Wo + (size_t)c * 256))[k4];
  if (c < 128) Wi1P[k4 * 128 + c] = ((const float4*)(Wi1 + (size_t)c * 256))[k4];
}

// ---------- 1. fused KV-projection + importance MLP ----------
__global__ __launch_bounds__(256) void kvimp_kernel(
    const float* __restrict__ X, const float4* __restrict__ WkP,
    const float* __restrict__ bk, const float4* __restrict__ WvP,
    const float* __restrict__ bv, const float4* __restrict__ Wi1P,
    const float* __restrict__ bi1, const float* __restrict__ Wi2,
    const float* __restrict__ bi2, float* __restrict__ Kout,
    float* __restrict__ Vout, float* __restrict__ imp) {
  __shared__ float xs[32][260];  // +4 pad: KV transpose reads 2-way max
  __shared__ float partial[4][16];
  int tid = threadIdx.x;
  if (blockIdx.x < 1024) {
    // ---- KV path (16 rows) ----
    int r0 = blockIdx.x * 16;
    const float4* Xv = (const float4*)(X + (size_t)r0 * 256);
    for (int n = tid; n < 1024; n += 256) {
      int row = n >> 6, sl = n & 63;
      ((float4*)xs[row])[sl] = Xv[row * 64 + sl];
    }
    __syncthreads();
    float ak[16], av[16];
#pragma unroll
    for (int tt = 0; tt < 16; ++tt) { ak[tt] = 0.f; av[tt] = 0.f; }
    for (int i4 = 0; i4 < 64; ++i4) {
      float4 wk = WkP[i4 * 256 + tid];  // coalesced panel loads
      float4 wv = WvP[i4 * 256 + tid];
#pragma unroll
      for (int tt = 0; tt < 16; ++tt) {
        float4 x = ((const float4*)xs[tt])[i4];
        ak[tt] += x.x * wk.x + x.y * wk.y + x.z * wk.z + x.w * wk.w;
        av[tt] += x.x * wv.x + x.y * wv.y + x.z * wv.z + x.w * wv.w;
      }
    }
    float bkj = bk[tid], bvj = bv[tid];
#pragma unroll 1
    for (int tt = 0; tt < 16; ++tt)
      Vout[(size_t)(r0 + tt) * 256 + tid] = av[tt] + bvj;
    __syncthreads();  // all FMA reads of xs done
#pragma unroll
    for (int tt = 0; tt < 16; ++tt) xs[tt][tid] = ak[tt] + bkj;
    __syncthreads();
    float4* K4v = (float4*)Kout;
#pragma unroll
    for (int i = 0; i < 4; ++i) {
      int idx = i * 256 + tid;
      int hd4 = idx >> 4, r = idx & 15;
      float4 kv = *(const float4*)&xs[r][hd4 * 4];
      K4v[(size_t)hd4 * T_TOK + r0 + r] = kv;
    }
  } else {
    // ---- imp path (32 tokens; grp g = tid>>7 owns tokens g*16..+15) ----
    int t0 = (blockIdx.x - 1024) * 32;
    const float4* Xv = (const float4*)(X + (size_t)t0 * 256);
    for (int n = tid; n < 2048; n += 256) {
      int row = n >> 6, sl = n & 63;
      ((float4*)xs[row])[sl] = Xv[row * 64 + sl];
    }
    __syncthreads();
    int j = tid & 127, grp = tid >> 7;
    float acc[16];
#pragma unroll
    for (int tt = 0; tt < 16; ++tt) acc[tt] = 0.f;
    for (int i4 = 0; i4 < 64; ++i4) {
      float4 w = Wi1P[i4 * 128 + j];
#pragma unroll
      for (int tt = 0; tt < 16; ++tt) {
        float4 x = ((const float4*)xs[grp * 16 + tt])[i4];
        acc[tt] += x.x * w.x + x.y * w.y + x.z * w.z + x.w * w.w;
      }
    }
    float b1 = bi1[j], w2 = Wi2[j];
    float p[16];
#pragma unroll
    for (int tt = 0; tt < 16; ++tt) {
      float hh = acc[tt] + b1;
      hh = hh > 0.f ? hh : 0.f;
      p[tt] = hh * w2;
    }
#pragma unroll
    for (int s = 1; s < 64; s <<= 1) {
#pragma unroll
      for (int tt = 0; tt < 16; ++tt) p[tt] += __shfl_xor(p[tt], s, 64);
    }
    int lane = tid & 63, wv_ = tid >> 6;
    if (lane == 0) {
#pragma unroll
      for (int tt = 0; tt < 16; ++tt) partial[wv_][tt] = p[tt];
    }
    __syncthreads();
    if (tid < 32) {
      int g = tid >> 4, tt = tid & 15;
      imp[t0 + g * 16 + tt] =
          partial[2 * g][tt] + partial[2 * g + 1][tt] + bi2[0];
    }
  }
}

// ---------- 2. top-6 select + Q projection (fused) + (block M_MSG) ranges ----------
__global__ __launch_bounds__(256) void topselq_kernel(
    const float* __restrict__ imp, const int* __restrict__ mb,
    const int* __restrict__ bidx, const float* __restrict__ X,
    const float4* __restrict__ WqP, const float* __restrict__ bq,
    int* __restrict__ selected, int* __restrict__ lo, int* __restrict__ hi,
    float* __restrict__ Qout) {
  int m = blockIdx.x;
  int tid = threadIdx.x;
  if (m == M_MSG) {  // fused ranges computation
    int g = tid;
    if (g < NBATCH) {
      int l = 0;
      while (l < M_MSG && bidx[l] < g) ++l;
      int h = l;
      while (h < M_MSG && bidx[h] == g) ++h;
      lo[g] = l * L_TOK;
      hi[g] = h * L_TOK;
    }
    return;
  }
  __shared__ int sel[KK];
  __shared__ float4 xs6[KK][64];  // 6 selected rows x 256 floats (full row)
  if (tid < 64) {  // wave 0: top-6 selection
    int l = tid;
    float myv = imp[m * 64 + l];
    int start = mb[2 * m];
    for (int k = 0; k < KK; ++k) {
      float rv = myv;
      int ri = l;
#pragma unroll
      for (int s = 1; s < 64; s <<= 1) {
        float ov = __shfl_xor(rv, s, 64);
        int oi = __shfl_xor(ri, s, 64);
        if (ov > rv || (ov == rv && oi < ri)) { rv = ov; ri = oi; }
      }
      if (l == 0) {
        selected[m * KK + k] = start + ri;
        sel[k] = start + ri;
      }
      if (l == ri) myv = -INFINITY;
    }
  }
  __syncthreads();
  for (int i = tid; i < KK * 64; i += 256) {  // stage full selected rows
    int r = i >> 6, d4 = i & 63;
    xs6[r][d4] = ((const float4*)X)[(size_t)sel[r] * 64 + d4];
  }
  __syncthreads();
  float acc[KK];
#pragma unroll
  for (int r = 0; r < KK; ++r) acc[r] = 0.f;
  for (int i4 = 0; i4 < 64; ++i4) {
    float4 w = WqP[i4 * 256 + tid];
#pragma unroll
    for (int r = 0; r < KK; ++r) {
      float4 x = xs6[r][i4];
      acc[r] += x.x * w.x + x.y * w.y + x.z * w.z + x.w * w.w;
    }
  }
  float bj = bq[tid];
#pragma unroll
  for (int r = 0; r < KK; ++r)
    Qout[(size_t)(m * KK + r) * 256 + tid] = (acc[r] + bj) * 0.125f;
}

// ---------- 5. scores + per-split top-10 (r2-proposed, 150.6us measured) ----------
// block = (m, h, split): 2048 blocks, 128 threads = 2 waves.
// Wave w owns queries w*3+{0,1,2}; lane L owns key base+L of each 64-key
// chunk. K dim-major K4[h*16+d4][T]: lane L's load of (d4, t=base+L) is
// 64x16B contiguous -> registers, no LDS staging of K, no hot-loop
// barriers. Q broadcast from LDS (conflict-free). Both waves stream the
// same keys (L1 sharing). Per-lane u64 top-10 lists + shfl extraction
// merge. __launch_bounds__(128,3) pins VGPR <= 170 (measured 168) so
// 3 waves/SIMD stay resident.
__global__ __launch_bounds__(128, 3) void scores_kernel(
    const float* __restrict__ Q, const float* __restrict__ K4,
    const int* __restrict__ lo_, const int* __restrict__ hi_,
    const int* __restrict__ bidx, unsigned long long* __restrict__ topk2) {
  int bid = blockIdx.x;
  // XCD swizzle: contiguous 256-block slab per XCD (bidx sorted).
  int sw = (bid & 7) * (M_MSG * NH * 2 / 8) + (bid >> 3);
  int m = sw >> 3;
  int h = (sw >> 1) & 3;
  int sp = sw & 1;
  int tid = threadIdx.x, lane = tid & 63, w = tid >> 6;
  int g = bidx[m];
  int lo = lo_[g], hi = hi_[g];
  int range = hi - lo;
  int n_all = (range + 63) >> 6;
  int n0 = (n_all + 1) >> 1;
  int nt = sp ? (n_all - n0) : n0;
  int start = lo + (sp ? n0 * 64 : 0);
  int end0 = lo + n0 * 64;
  int end = sp ? hi : (end0 < hi ? end0 : hi);

  __shared__ float4 qs4[KK][16];  // 6 queries x 64 dims (1.5 KB)
  const float4* Qv = (const float4*)Q;
  for (int i = tid; i < KK * 16; i += 128) {
    int qq = i >> 4, d4 = i & 15;
    qs4[qq][d4] = Qv[(size_t)(m * KK + qq) * 64 + h * 16 + d4];
  }
  __syncthreads();

  unsigned long long lst[3][KT];
#pragma unroll
  for (int j = 0; j < 3; ++j)
#pragma unroll
    for (int k = 0; k < KT; ++k) lst[j][k] = 0ULL;

  const float4* Kh = (const float4*)K4 + (size_t)h * 16 * T_TOK;

#pragma unroll 1
  for (int kb = 0; kb < nt; ++kb) {
    int t = start + kb * 64 + lane;
    int tc = t < hi ? t : hi - 1;
    float acc[3];
    acc[0] = 0.f; acc[1] = 0.f; acc[2] = 0.f;
#pragma unroll
    for (int half = 0; half < 2; ++half) {
      float4 ka[8];
#pragma unroll
      for (int d = 0; d < 8; ++d)
        ka[d] = Kh[(size_t)(half * 8 + d) * T_TOK + tc];
#pragma unroll
      for (int d = 0; d < 8; ++d) {
#pragma unroll
        for (int j = 0; j < 3; ++j) {
          float4 q = qs4[w * 3 + j][half * 8 + d];
          acc[j] += ka[d].x * q.x + ka[d].y * q.y + ka[d].z * q.z +
                    ka[d].w * q.w;
        }
      }
    }
    bool v0 = (t < end) && ((t >> 6) != m);
    unsigned nk = ~(unsigned)t;
#pragma unroll
    for (int j = 0; j < 3; ++j) {
      unsigned cc = v0 ? ordf(acc[j]) : 0u;
      unsigned long long key =
          cc ? (((unsigned long long)cc << 32) | nk) : 0ULL;
      if (key > lst[j][KT - 1]) {
        unsigned long long ins = key;
#pragma unroll
        for (int r = 0; r < KT; ++r) {
          unsigned long long cur = lst[j][r];
          unsigned long long mx = ins > cur ? ins : cur;
          unsigned long long mn = ins > cur ? cur : ins;
          lst[j][r] = mx;
          ins = mn;
        }
      }
    }
  }

  // ---- extraction merge across 64 lanes (3 queries interleaved for ILP) ----
  for (int k = 0; k < KT; ++k) {
    unsigned long long mx[3];
#pragma unroll
    for (int j = 0; j < 3; ++j) mx[j] = lst[j][0];
#pragma unroll
    for (int s_ = 1; s_ < 64; s_ <<= 1) {
#pragma unroll
      for (int j = 0; j < 3; ++j) {
        unsigned long long o = __shfl_xor(mx[j], s_, 64);
        if (o > mx[j]) mx[j] = o;
      }
    }
#pragma unroll
    for (int j = 0; j < 3; ++j) {
      if (mx[j] != 0ULL && lst[j][0] == mx[j]) {
#pragma unroll
        for (int r = 0; r < KT - 1; ++r) lst[j][r] = lst[j][r + 1];
        lst[j][KT - 1] = 0ULL;
      }
    }
    if (lane == 0) {
#pragma unroll
      for (int j = 0; j < 3; ++j) {
        int q = m * KK + w * 3 + j;
        topk2[((size_t)(q * NH + h) * 2 + sp) * KT + k] = mx[j];
      }
    }
  }
}

// ---------- 6. merge splits + softmax + gather V + Wo + scatter-add + avg ----------
__global__ __launch_bounds__(256) void finish_kernel(
    const unsigned long long* __restrict__ topk2, const float* __restrict__ V,
    const float4* __restrict__ WoP, const float* __restrict__ bo,
    const int* __restrict__ selected, float* __restrict__ out,
    float* __restrict__ out_avg) {
  int q0 = blockIdx.x * 16;
  int tid = threadIdx.x;
  __shared__ unsigned long long buf[64][2 * KT];  // 10 KB
  __shared__ float tvs[16][NH][KT];
  __shared__ int tis[16][NH][KT];
  __shared__ float wsm[16][NH * KT];
  __shared__ float att[16][256];
  // stage the 64 (q,h) pairs' split lists
  const unsigned long long* src = topk2 + (size_t)q0 * NH * 2 * KT;
  for (int i = tid; i < 64 * 2 * KT; i += 256) (&buf[0][0])[i] = src[i];
  __syncthreads();
  if (tid < 64) {
    int qq = tid >> 2, h = tid & 3;
    // two-pointer exact merge of the two sorted-desc lists + inline softmax
    int pa = 0, pb = 0;
    float e[KT];
    float m0 = 0.f, sum = 0.f;
#pragma unroll
    for (int k = 0; k < KT; ++k) {
      unsigned long long va = buf[tid][pa];
      unsigned long long vb = buf[tid][KT + pb];
      unsigned long long v;
      if (va >= vb) { v = va; ++pa; } else { v = vb; ++pb; }
      float scv;
      int t;
      if (v != 0ULL) {
        scv = unordf((unsigned)(v >> 32));
        t = (int)(~(unsigned)v);
      } else {
        scv = -1e30f;
        t = 0;
      }
      tvs[qq][h][k] = scv;
      tis[qq][h][k] = t;
      if (k == 0) m0 = scv;
      e[k] = expf(scv - m0);
      sum += e[k];
    }
    float inv = 1.f / sum;
#pragma unroll
    for (int k = 0; k < KT; ++k) wsm[qq][h * KT + k] = e[k] * inv;
  }
  __syncthreads();
  if (tid < 160) {
    int qq = tid / 10, k = tid % 10;
    out_avg[(size_t)(q0 + qq) * KT + k] =
        0.25f * (tvs[qq][0][k] + tvs[qq][1][k] + tvs[qq][2][k] + tvs[qq][3][k]);
  }
  int h = tid >> 6, d = tid & 63;
#pragma unroll 1
  for (int qq = 0; qq < 16; ++qq) {
    float a = 0.f;
#pragma unroll
    for (int k = 0; k < KT; ++k) {
      int t = tis[qq][h][k];
      a += wsm[qq][h * KT + k] * V[(size_t)t * 256 + h * 64 + d];
    }
    att[qq][tid] = a;
  }
  __syncthreads();
  float acc[16];
#pragma unroll
  for (int tt = 0; tt < 16; ++tt) acc[tt] = 0.f;
  for (int i4 = 0; i4 < 64; ++i4) {
    float4 wv = WoP[i4 * 256 + tid];  // coalesced panel load
#pragma unroll
    for (int tt = 0; tt < 16; ++tt) {
      float4 x = ((const float4*)att[tt])[i4];
      acc[tt] += x.x * wv.x + x.y * wv.y + x.z * wv.z + x.w * wv.w;
    }
  }
  float bj = bo[tid];
#pragma unroll 1
  for (int tt = 0; tt < 16; ++tt) {
    int s = selected[q0 + tt];
    out[(size_t)s * 256 + tid] += acc[tt] + bj;
  }
}

// ---------- launch ----------
extern "C" void kernel_launch(void* const* d_in, const int* in_sizes, int n_in,
                              void* d_out, int out_size, void* d_ws, size_t ws_size,
                              hipStream_t stream) {
  const float* X   = (const float*)d_in[0];
  const int*   mb  = (const int*)d_in[1];
  const int*   bidx= (const int*)d_in[2];
  const float* Wq  = (const float*)d_in[3];
  const float* bq  = (const float*)d_in[4];
  const float* Wk  = (const float*)d_in[5];
  const float* bk  = (const float*)d_in[6];
  const float* Wv  = (const float*)d_in[7];
  const float* bv  = (const float*)d_in[8];
  const float* Wi1 = (const float*)d_in[9];
  const float* bi1 = (const float*)d_in[10];
  const float* Wi2 = (const float*)d_in[11];
  const float* bi2 = (const float*)d_in[12];
  const float* Wo  = (const float*)d_in[13];
  const float* bo  = (const float*)d_in[14];

  float* out = (float*)d_out;
  float* out_avg = out + (size_t)T_TOK * D_HID;

  // K is staged in d_out's "updated" region (dead until final memcpy+scatter).
  float* Kmat = out;

  char* ws = (char*)d_ws;
  size_t off = 0;
  float* V = (float*)(ws + off);        off += (size_t)T_TOK * 256 * 4;   // 16.78 MB
  float* Q = (float*)(ws + off);        off += (size_t)NQ * 256 * 4;      // 1.57 MB
  float* imp = (float*)(ws + off);      off += (size_t)T_TOK * 4;
  int* selected = (int*)(ws + off);     off += (size_t)NQ * 4;
  int* lo = (int*)(ws + off);           off += 64;
  int* hi = (int*)(ws + off);           off += 64;
  unsigned long long* topk2 = (unsigned long long*)(ws + off);
  off += (size_t)NQ * NH * 2 * KT * 8;                                    // 0.98 MB
  float4* WkP = (float4*)(ws + off);    off += (size_t)64 * 256 * 16;     // 256 KB
  float4* WvP = (float4*)(ws + off);    off += (size_t)64 * 256 * 16;
  float4* WqP = (float4*)(ws + off);    off += (size_t)64 * 256 * 16;
  float4* WoP = (float4*)(ws + off);    off += (size_t)64 * 256 * 16;
  float4* Wi1P = (float4*)(ws + off);   off += (size_t)64 * 128 * 16;     // 128 KB
  (void)ws_size; (void)in_sizes; (void)n_in; (void)out_size;

  wpanel_kernel<<<256, 64, 0, stream>>>(Wk, Wv, Wq, Wo, Wi1, WkP, WvP, WqP,
                                        WoP, Wi1P);
  kvimp_kernel<<<1536, 256, 0, stream>>>(X, WkP, bk, WvP, bv, Wi1P, bi1, Wi2,
                                         bi2, Kmat, V, imp);
  topselq_kernel<<<M_MSG + 1, 256, 0, stream>>>(imp, mb, bidx, X, WqP, bq,
                                                selected, lo, hi, Q);
  scores_kernel<<<M_MSG * NH * 2, 128, 0, stream>>>(Q, Kmat, lo, hi, bidx,
                                                    topk2);
  hipMemcpyAsync(out, X, (size_t)T_TOK * D_HID * sizeof(float),
                 hipMemcpyDeviceToDevice, stream);
  finish_kernel<<<NQ / 16, 256, 0, stream>>>(topk2, V, WoP, bo, selected, out,
                                             out_avg);
}

// Round 14
// 309.984 us; speedup vs baseline: 1.7406x; 1.7406x over previous
//
#include <hip/hip_runtime.h>
#include <math.h>

#define T_TOK 16384
#define M_MSG 256
#define L_TOK 64
#define KK 6
#define NQ (M_MSG * KK)   // 1536
#define D_HID 256
#define NH 4
#define HD 64
#define KT 10
#define NBATCH 8

// ---------- helpers ----------
__device__ __forceinline__ unsigned ordf(float f) {
  unsigned u = __float_as_uint(f);
  return (u & 0x80000000u) ? ~u : (u | 0x80000000u);
}
__device__ __forceinline__ float unordf(unsigned u) {
  return __uint_as_float((u & 0x80000000u) ? (u ^ 0x80000000u) : ~u);
}

// ---------- 0. weight k-panel transpose ----------
__global__ __launch_bounds__(64) void wpanel_kernel(
    const float* __restrict__ Wk, const float* __restrict__ Wv,
    const float* __restrict__ Wq, const float* __restrict__ Wo,
    const float* __restrict__ Wi1, float4* __restrict__ WkP,
    float4* __restrict__ WvP, float4* __restrict__ WqP,
    float4* __restrict__ WoP, float4* __restrict__ Wi1P) {
  int c = blockIdx.x;    // 0..255 (column)
  int k4 = threadIdx.x;  // 0..63 (dim group)
  WkP[k4 * 256 + c] = ((const float4*)(Wk + (size_t)c * 256))[k4];
  WvP[k4 * 256 + c] = ((const float4*)(Wv + (size_t)c * 256))[k4];
  WqP[k4 * 256 + c] = ((const float4*)(Wq + (size_t)c * 256))[k4];
  WoP[k4 * 256 + c] = ((const float4*)(Wo + (size_t)c * 256))[k4];
  if (c < 128) Wi1P[k4 * 128 + c] = ((const float4*)(Wi1 + (size_t)c * 256))[k4];
}

// ---------- 1. fused KV-projection + importance MLP ----------
__global__ __launch_bounds__(256) void kvimp_kernel(
    const float* __restrict__ X, const float4* __restrict__ WkP,
    const float* __restrict__ bk, const float4* __restrict__ WvP,
    const float* __restrict__ bv, const float4* __restrict__ Wi1P,
    const float* __restrict__ bi1, const float* __restrict__ Wi2,
    const float* __restrict__ bi2, float* __restrict__ Kout,
    float* __restrict__ Vout, float* __restrict__ imp) {
  __shared__ float xs[32][260];  // +4 pad: KV transpose reads 2-way max
  __shared__ float partial[4][16];
  int tid = threadIdx.x;
  if (blockIdx.x < 1024) {
    // ---- KV path (16 rows) ----
    int r0 = blockIdx.x * 16;
    const float4* Xv = (const float4*)(X + (size_t)r0 * 256);
    for (int n = tid; n < 1024; n += 256) {
      int row = n >> 6, sl = n & 63;
      ((float4*)xs[row])[sl] = Xv[row * 64 + sl];
    }
    __syncthreads();
    float ak[16], av[16];
#pragma unroll
    for (int tt = 0; tt < 16; ++tt) { ak[tt] = 0.f; av[tt] = 0.f; }
    for (int i4 = 0; i4 < 64; ++i4) {
      float4 wk = WkP[i4 * 256 + tid];  // coalesced panel loads
      float4 wv = WvP[i4 * 256 + tid];
#pragma unroll
      for (int tt = 0; tt < 16; ++tt) {
        float4 x = ((const float4*)xs[tt])[i4];
        ak[tt] += x.x * wk.x + x.y * wk.y + x.z * wk.z + x.w * wk.w;
        av[tt] += x.x * wv.x + x.y * wv.y + x.z * wv.z + x.w * wv.w;
      }
    }
    float bkj = bk[tid], bvj = bv[tid];
#pragma unroll 1
    for (int tt = 0; tt < 16; ++tt)
      Vout[(size_t)(r0 + tt) * 256 + tid] = av[tt] + bvj;
    __syncthreads();  // all FMA reads of xs done
#pragma unroll
    for (int tt = 0; tt < 16; ++tt) xs[tt][tid] = ak[tt] + bkj;
    __syncthreads();
    float4* K4v = (float4*)Kout;
#pragma unroll
    for (int i = 0; i < 4; ++i) {
      int idx = i * 256 + tid;
      int hd4 = idx >> 4, r = idx & 15;
      float4 kv = *(const float4*)&xs[r][hd4 * 4];
      K4v[(size_t)hd4 * T_TOK + r0 + r] = kv;
    }
  } else {
    // ---- imp path (32 tokens; grp g = tid>>7 owns tokens g*16..+15) ----
    int t0 = (blockIdx.x - 1024) * 32;
    const float4* Xv = (const float4*)(X + (size_t)t0 * 256);
    for (int n = tid; n < 2048; n += 256) {
      int row = n >> 6, sl = n & 63;
      ((float4*)xs[row])[sl] = Xv[row * 64 + sl];
    }
    __syncthreads();
    int j = tid & 127, grp = tid >> 7;
    float acc[16];
#pragma unroll
    for (int tt = 0; tt < 16; ++tt) acc[tt] = 0.f;
    for (int i4 = 0; i4 < 64; ++i4) {
      float4 w = Wi1P[i4 * 128 + j];
#pragma unroll
      for (int tt = 0; tt < 16; ++tt) {
        float4 x = ((const float4*)xs[grp * 16 + tt])[i4];
        acc[tt] += x.x * w.x + x.y * w.y + x.z * w.z + x.w * w.w;
      }
    }
    float b1 = bi1[j], w2 = Wi2[j];
    float p[16];
#pragma unroll
    for (int tt = 0; tt < 16; ++tt) {
      float hh = acc[tt] + b1;
      hh = hh > 0.f ? hh : 0.f;
      p[tt] = hh * w2;
    }
#pragma unroll
    for (int s = 1; s < 64; s <<= 1) {
#pragma unroll
      for (int tt = 0; tt < 16; ++tt) p[tt] += __shfl_xor(p[tt], s, 64);
    }
    int lane = tid & 63, wv_ = tid >> 6;
    if (lane == 0) {
#pragma unroll
      for (int tt = 0; tt < 16; ++tt) partial[wv_][tt] = p[tt];
    }
    __syncthreads();
    if (tid < 32) {
      int g = tid >> 4, tt = tid & 15;
      imp[t0 + g * 16 + tt] =
          partial[2 * g][tt] + partial[2 * g + 1][tt] + bi2[0];
    }
  }
}

// ---------- 2. top-6 select + Q projection (fused) + (block M_MSG) ranges ----------
__global__ __launch_bounds__(256) void topselq_kernel(
    const float* __restrict__ imp, const int* __restrict__ mb,
    const int* __restrict__ bidx, const float* __restrict__ X,
    const float4* __restrict__ WqP, const float* __restrict__ bq,
    int* __restrict__ selected, int* __restrict__ lo, int* __restrict__ hi,
    float* __restrict__ Qout) {
  int m = blockIdx.x;
  int tid = threadIdx.x;
  if (m == M_MSG) {  // fused ranges computation
    int g = tid;
    if (g < NBATCH) {
      int l = 0;
      while (l < M_MSG && bidx[l] < g) ++l;
      int h = l;
      while (h < M_MSG && bidx[h] == g) ++h;
      lo[g] = l * L_TOK;
      hi[g] = h * L_TOK;
    }
    return;
  }
  __shared__ int sel[KK];
  __shared__ float4 xs6[KK][64];  // 6 selected rows x 256 floats (full row)
  if (tid < 64) {  // wave 0: top-6 selection
    int l = tid;
    float myv = imp[m * 64 + l];
    int start = mb[2 * m];
    for (int k = 0; k < KK; ++k) {
      float rv = myv;
      int ri = l;
#pragma unroll
      for (int s = 1; s < 64; s <<= 1) {
        float ov = __shfl_xor(rv, s, 64);
        int oi = __shfl_xor(ri, s, 64);
        if (ov > rv || (ov == rv && oi < ri)) { rv = ov; ri = oi; }
      }
      if (l == 0) {
        selected[m * KK + k] = start + ri;
        sel[k] = start + ri;
      }
      if (l == ri) myv = -INFINITY;
    }
  }
  __syncthreads();
  for (int i = tid; i < KK * 64; i += 256) {  // stage full selected rows
    int r = i >> 6, d4 = i & 63;
    xs6[r][d4] = ((const float4*)X)[(size_t)sel[r] * 64 + d4];
  }
  __syncthreads();
  float acc[KK];
#pragma unroll
  for (int r = 0; r < KK; ++r) acc[r] = 0.f;
  for (int i4 = 0; i4 < 64; ++i4) {
    float4 w = WqP[i4 * 256 + tid];
#pragma unroll
    for (int r = 0; r < KK; ++r) {
      float4 x = xs6[r][i4];
      acc[r] += x.x * w.x + x.y * w.y + x.z * w.z + x.w * w.w;
    }
  }
  float bj = bq[tid];
#pragma unroll
  for (int r = 0; r < KK; ++r)
    Qout[(size_t)(m * KK + r) * 256 + tid] = (acc[r] + bj) * 0.125f;
}

// ---------- 5. scores + per-split top-10 (r3-measured 150.6us variant) ----------
// block = (m, h, split): 2048 blocks, 128 threads = 2 waves.
// Wave w owns queries w*3+{0,1,2}; lane L owns key base+L of each 64-key
// chunk. K dim-major K4[h*16+d4][T]: lane L's load of (d4, t=base+L) is
// 64x16B contiguous -> registers, no LDS staging of K, no hot-loop
// barriers. Q broadcast from LDS (conflict-free). Both waves stream the
// same keys (L1 sharing). Per-lane u64 top-10 lists + shfl extraction
// merge. Natural register allocation (168 VGPR measured) -- NO min-waves
// launch_bounds (r13's (128,3) squeezed to 84 VGPR and spilled 697 MB).
__global__ __launch_bounds__(128) void scores_kernel(
    const float* __restrict__ Q, const float* __restrict__ K4,
    const int* __restrict__ lo_, const int* __restrict__ hi_,
    const int* __restrict__ bidx, unsigned long long* __restrict__ topk2) {
  int bid = blockIdx.x;
  // XCD swizzle: contiguous 256-block slab per XCD (bidx sorted).
  int sw = (bid & 7) * (M_MSG * NH * 2 / 8) + (bid >> 3);
  int m = sw >> 3;
  int h = (sw >> 1) & 3;
  int sp = sw & 1;
  int tid = threadIdx.x, lane = tid & 63, w = tid >> 6;
  int g = bidx[m];
  int lo = lo_[g], hi = hi_[g];
  int range = hi - lo;
  int n_all = (range + 63) >> 6;
  int n0 = (n_all + 1) >> 1;
  int nt = sp ? (n_all - n0) : n0;
  int start = lo + (sp ? n0 * 64 : 0);
  int end0 = lo + n0 * 64;
  int end = sp ? hi : (end0 < hi ? end0 : hi);

  __shared__ float4 qs4[KK][16];  // 6 queries x 64 dims (1.5 KB)
  const float4* Qv = (const float4*)Q;
  for (int i = tid; i < KK * 16; i += 128) {
    int qq = i >> 4, d4 = i & 15;
    qs4[qq][d4] = Qv[(size_t)(m * KK + qq) * 64 + h * 16 + d4];
  }
  __syncthreads();

  unsigned long long lst[3][KT];
#pragma unroll
  for (int j = 0; j < 3; ++j)
#pragma unroll
    for (int k = 0; k < KT; ++k) lst[j][k] = 0ULL;

  const float4* Kh = (const float4*)K4 + (size_t)h * 16 * T_TOK;

#pragma unroll 1
  for (int kb = 0; kb < nt; ++kb) {
    int t = start + kb * 64 + lane;
    int tc = t < hi ? t : hi - 1;
    float acc[3];
    acc[0] = 0.f; acc[1] = 0.f; acc[2] = 0.f;
#pragma unroll
    for (int half = 0; half < 2; ++half) {
      float4 ka[8];
#pragma unroll
      for (int d = 0; d < 8; ++d)
        ka[d] = Kh[(size_t)(half * 8 + d) * T_TOK + tc];
#pragma unroll
      for (int d = 0; d < 8; ++d) {
#pragma unroll
        for (int j = 0; j < 3; ++j) {
          float4 q = qs4[w * 3 + j][half * 8 + d];
          acc[j] += ka[d].x * q.x + ka[d].y * q.y + ka[d].z * q.z +
                    ka[d].w * q.w;
        }
      }
    }
    bool v0 = (t < end) && ((t >> 6) != m);
    unsigned nk = ~(unsigned)t;
#pragma unroll
    for (int j = 0; j < 3; ++j) {
      unsigned cc = v0 ? ordf(acc[j]) : 0u;
      unsigned long long key =
          cc ? (((unsigned long long)cc << 32) | nk) : 0ULL;
      if (key > lst[j][KT - 1]) {
        unsigned long long ins = key;
#pragma unroll
        for (int r = 0; r < KT; ++r) {
          unsigned long long cur = lst[j][r];
          unsigned long long mx = ins > cur ? ins : cur;
          unsigned long long mn = ins > cur ? cur : ins;
          lst[j][r] = mx;
          ins = mn;
        }
      }
    }
  }

  // ---- extraction merge across 64 lanes (3 queries interleaved for ILP) ----
  for (int k = 0; k < KT; ++k) {
    unsigned long long mx[3];
#pragma unroll
    for (int j = 0; j < 3; ++j) mx[j] = lst[j][0];
#pragma unroll
    for (int s_ = 1; s_ < 64; s_ <<= 1) {
#pragma unroll
      for (int j = 0; j < 3; ++j) {
        unsigned long long o = __shfl_xor(mx[j], s_, 64);
        if (o > mx[j]) mx[j] = o;
      }
    }
#pragma unroll
    for (int j = 0; j < 3; ++j) {
      if (mx[j] != 0ULL && lst[j][0] == mx[j]) {
#pragma unroll
        for (int r = 0; r < KT - 1; ++r) lst[j][r] = lst[j][r + 1];
        lst[j][KT - 1] = 0ULL;
      }
    }
    if (lane == 0) {
#pragma unroll
      for (int j = 0; j < 3; ++j) {
        int q = m * KK + w * 3 + j;
        topk2[((size_t)(q * NH + h) * 2 + sp) * KT + k] = mx[j];
      }
    }
  }
}

// ---------- 6. merge splits + softmax + gather V + Wo + scatter-add + avg ----------
__global__ __launch_bounds__(256) void finish_kernel(
    const unsigned long long* __restrict__ topk2, const float* __restrict__ V,
    const float4* __restrict__ WoP, const float* __restrict__ bo,
    const int* __restrict__ selected, float* __restrict__ out,
    float* __restrict__ out_avg) {
  int q0 = blockIdx.x * 16;
  int tid = threadIdx.x;
  __shared__ unsigned long long buf[64][2 * KT];  // 10 KB
  __shared__ float tvs[16][NH][KT];
  __shared__ int tis[16][NH][KT];
  __shared__ float wsm[16][NH * KT];
  __shared__ float att[16][256];
  // stage the 64 (q,h) pairs' split lists
  const unsigned long long* src = topk2 + (size_t)q0 * NH * 2 * KT;
  for (int i = tid; i < 64 * 2 * KT; i += 256) (&buf[0][0])[i] = src[i];
  __syncthreads();
  if (tid < 64) {
    int qq = tid >> 2, h = tid & 3;
    // two-pointer exact merge of the two sorted-desc lists + inline softmax
    int pa = 0, pb = 0;
    float e[KT];
    float m0 = 0.f, sum = 0.f;
#pragma unroll
    for (int k = 0; k < KT; ++k) {
      unsigned long long va = buf[tid][pa];
      unsigned long long vb = buf[tid][KT + pb];
      unsigned long long v;
      if (va >= vb) { v = va; ++pa; } else { v = vb; ++pb; }
      float scv;
      int t;
      if (v != 0ULL) {
        scv = unordf((unsigned)(v >> 32));
        t = (int)(~(unsigned)v);
      } else {
        scv = -1e30f;
        t = 0;
      }
      tvs[qq][h][k] = scv;
      tis[qq][h][k] = t;
      if (k == 0) m0 = scv;
      e[k] = expf(scv - m0);
      sum += e[k];
    }
    float inv = 1.f / sum;
#pragma unroll
    for (int k = 0; k < KT; ++k) wsm[qq][h * KT + k] = e[k] * inv;
  }
  __syncthreads();
  if (tid < 160) {
    int qq = tid / 10, k = tid % 10;
    out_avg[(size_t)(q0 + qq) * KT + k] =
        0.25f * (tvs[qq][0][k] + tvs[qq][1][k] + tvs[qq][2][k] + tvs[qq][3][k]);
  }
  int h = tid >> 6, d = tid & 63;
#pragma unroll 1
  for (int qq = 0; qq < 16; ++qq) {
    float a = 0.f;
#pragma unroll
    for (int k = 0; k < KT; ++k) {
      int t = tis[qq][h][k];
      a += wsm[qq][h * KT + k] * V[(size_t)t * 256 + h * 64 + d];
    }
    att[qq][tid] = a;
  }
  __syncthreads();
  float acc[16];
#pragma unroll
  for (int tt = 0; tt < 16; ++tt) acc[tt] = 0.f;
  for (int i4 = 0; i4 < 64; ++i4) {
    float4 wv = WoP[i4 * 256 + tid];  // coalesced panel load
#pragma unroll
    for (int tt = 0; tt < 16; ++tt) {
      float4 x = ((const float4*)att[tt])[i4];
      acc[tt] += x.x * wv.x + x.y * wv.y + x.z * wv.z + x.w * wv.w;
    }
  }
  float bj = bo[tid];
#pragma unroll 1
  for (int tt = 0; tt < 16; ++tt) {
    int s = selected[q0 + tt];
    out[(size_t)s * 256 + tid] += acc[tt] + bj;
  }
}

// ---------- launch ----------
extern "C" void kernel_launch(void* const* d_in, const int* in_sizes, int n_in,
                              void* d_out, int out_size, void* d_ws, size_t ws_size,
                              hipStream_t stream) {
  const float* X   = (const float*)d_in[0];
  const int*   mb  = (const int*)d_in[1];
  const int*   bidx= (const int*)d_in[2];
  const float* Wq  = (const float*)d_in[3];
  const float* bq  = (const float*)d_in[4];
  const float* Wk  = (const float*)d_in[5];
  const float* bk  = (const float*)d_in[6];
  const float* Wv  = (const float*)d_in[7];
  const float* bv  = (const float*)d_in[8];
  const float* Wi1 = (const float*)d_in[9];
  const float* bi1 = (const float*)d_in[10];
  const float* Wi2 = (const float*)d_in[11];
  const float* bi2 = (const float*)d_in[12];
  const float* Wo  = (const float*)d_in[13];
  const float* bo  = (const float*)d_in[14];

  float* out = (float*)d_out;
  float* out_avg = out + (size_t)T_TOK * D_HID;

  // K is staged in d_out's "updated" region (dead until final memcpy+scatter).
  float* Kmat = out;

  char* ws = (char*)d_ws;
  size_t off = 0;
  float* V = (float*)(ws + off);        off += (size_t)T_TOK * 256 * 4;   // 16.78 MB
  float* Q = (float*)(ws + off);        off += (size_t)NQ * 256 * 4;      // 1.57 MB
  float* imp = (float*)(ws + off);      off += (size_t)T_TOK * 4;
  int* selected = (int*)(ws + off);     off += (size_t)NQ * 4;
  int* lo = (int*)(ws + off);           off += 64;
  int* hi = (int*)(ws + off);           off += 64;
  unsigned long long* topk2 = (unsigned long long*)(ws + off);
  off += (size_t)NQ * NH * 2 * KT * 8;                                    // 0.98 MB
  float4* WkP = (float4*)(ws + off);    off += (size_t)64 * 256 * 16;     // 256 KB
  float4* WvP = (float4*)(ws + off);    off += (size_t)64 * 256 * 16;
  float4* WqP = (float4*)(ws + off);    off += (size_t)64 * 256 * 16;
  float4* WoP = (float4*)(ws + off);    off += (size_t)64 * 256 * 16;
  float4* Wi1P = (float4*)(ws + off);   off += (size_t)64 * 128 * 16;     // 128 KB
  (void)ws_size; (void)in_sizes; (void)n_in; (void)out_size;

  wpanel_kernel<<<256, 64, 0, stream>>>(Wk, Wv, Wq, Wo, Wi1, WkP, WvP, WqP,
                                        WoP, Wi1P);
  kvimp_kernel<<<1536, 256, 0, stream>>>(X, WkP, bk, WvP, bv, Wi1P, bi1, Wi2,
                                         bi2, Kmat, V, imp);
  topselq_kernel<<<M_MSG + 1, 256, 0, stream>>>(imp, mb, bidx, X, WqP, bq,
                                                selected, lo, hi, Q);
  scores_kernel<<<M_MSG * NH * 2, 128, 0, stream>>>(Q, Kmat, lo, hi, bidx,
                                                    topk2);
  hipMemcpyAsync(out, X, (size_t)T_TOK * D_HID * sizeof(float),
                 hipMemcpyDeviceToDevice, stream);
  finish_kernel<<<NQ / 16, 256, 0, stream>>>(topk2, V, WoP, bo, selected, out,
                                             out_avg);
}

// Round 15
// 299.834 us; speedup vs baseline: 1.7996x; 1.0339x over previous
//
#include <hip/hip_runtime.h>
#include <math.h>

#define T_TOK 16384
#define M_MSG 256
#define L_TOK 64
#define KK 6
#define NQ (M_MSG * KK)   // 1536
#define D_HID 256
#define NH 4
#define HD 64
#define KT 10
#define NBATCH 8

// ---------- helpers ----------
__device__ __forceinline__ unsigned ordf(float f) {
  unsigned u = __float_as_uint(f);
  return (u & 0x80000000u) ? ~u : (u | 0x80000000u);
}
__device__ __forceinline__ float unordf(unsigned u) {
  return __uint_as_float((u & 0x80000000u) ? (u ^ 0x80000000u) : ~u);
}
__device__ __forceinline__ unsigned f2bf(float x) {  // RNE float->bf16 bits
  unsigned u = __float_as_uint(x);
  return (u + 0x7FFFu + ((u >> 16) & 1u)) >> 16;
}
__device__ __forceinline__ float bflo(unsigned u) {  // low bf16 -> float
  return __uint_as_float(u << 16);
}
__device__ __forceinline__ float bfhi(unsigned u) {  // high bf16 -> float
  return __uint_as_float(u & 0xFFFF0000u);
}

// ---------- 0. weight k-panel transpose ----------
__global__ __launch_bounds__(64) void wpanel_kernel(
    const float* __restrict__ Wk, const float* __restrict__ Wv,
    const float* __restrict__ Wq, const float* __restrict__ Wo,
    const float* __restrict__ Wi1, float4* __restrict__ WkP,
    float4* __restrict__ WvP, float4* __restrict__ WqP,
    float4* __restrict__ WoP, float4* __restrict__ Wi1P) {
  int c = blockIdx.x;    // 0..255 (column)
  int k4 = threadIdx.x;  // 0..63 (dim group)
  WkP[k4 * 256 + c] = ((const float4*)(Wk + (size_t)c * 256))[k4];
  WvP[k4 * 256 + c] = ((const float4*)(Wv + (size_t)c * 256))[k4];
  WqP[k4 * 256 + c] = ((const float4*)(Wq + (size_t)c * 256))[k4];
  WoP[k4 * 256 + c] = ((const float4*)(Wo + (size_t)c * 256))[k4];
  if (c < 128) Wi1P[k4 * 128 + c] = ((const float4*)(Wi1 + (size_t)c * 256))[k4];
}

// ---------- 1. fused KV-projection + importance MLP ----------
// K output is now bf16, packed dim-major: Kb[h*8+d8][t] = uint4 holding
// dims d8*8..d8*8+7 of token t (RNE-rounded). V stays fp32 row-major.
__global__ __launch_bounds__(256) void kvimp_kernel(
    const float* __restrict__ X, const float4* __restrict__ WkP,
    const float* __restrict__ bk, const float4* __restrict__ WvP,
    const float* __restrict__ bv, const float4* __restrict__ Wi1P,
    const float* __restrict__ bi1, const float* __restrict__ Wi2,
    const float* __restrict__ bi2, unsigned* __restrict__ Kout,
    float* __restrict__ Vout, float* __restrict__ imp) {
  __shared__ float xs[32][260];  // +4 pad: KV transpose reads spread banks
  __shared__ float partial[4][16];
  int tid = threadIdx.x;
  if (blockIdx.x < 1024) {
    // ---- KV path (16 rows) ----
    int r0 = blockIdx.x * 16;
    const float4* Xv = (const float4*)(X + (size_t)r0 * 256);
    for (int n = tid; n < 1024; n += 256) {
      int row = n >> 6, sl = n & 63;
      ((float4*)xs[row])[sl] = Xv[row * 64 + sl];
    }
    __syncthreads();
    float ak[16], av[16];
#pragma unroll
    for (int tt = 0; tt < 16; ++tt) { ak[tt] = 0.f; av[tt] = 0.f; }
    for (int i4 = 0; i4 < 64; ++i4) {
      float4 wk = WkP[i4 * 256 + tid];  // coalesced panel loads
      float4 wv = WvP[i4 * 256 + tid];
#pragma unroll
      for (int tt = 0; tt < 16; ++tt) {
        float4 x = ((const float4*)xs[tt])[i4];
        ak[tt] += x.x * wk.x + x.y * wk.y + x.z * wk.z + x.w * wk.w;
        av[tt] += x.x * wv.x + x.y * wv.y + x.z * wv.z + x.w * wv.w;
      }
    }
    float bkj = bk[tid], bvj = bv[tid];
#pragma unroll 1
    for (int tt = 0; tt < 16; ++tt)
      Vout[(size_t)(r0 + tt) * 256 + tid] = av[tt] + bvj;
    __syncthreads();  // all FMA reads of xs done
#pragma unroll
    for (int tt = 0; tt < 16; ++tt) xs[tt][tid] = ak[tt] + bkj;
    __syncthreads();
    uint4* Kbv = (uint4*)Kout;
#pragma unroll
    for (int i = 0; i < 2; ++i) {
      int idx = i * 256 + tid;    // 0..511
      int hd8 = idx >> 4;         // 0..31 (h*8 + d8)
      int r = idx & 15;
      const float* row = &xs[r][hd8 * 8];
      uint4 p;
      p.x = f2bf(row[0]) | (f2bf(row[1]) << 16);
      p.y = f2bf(row[2]) | (f2bf(row[3]) << 16);
      p.z = f2bf(row[4]) | (f2bf(row[5]) << 16);
      p.w = f2bf(row[6]) | (f2bf(row[7]) << 16);
      Kbv[(size_t)hd8 * T_TOK + r0 + r] = p;
    }
  } else {
    // ---- imp path (32 tokens; grp g = tid>>7 owns tokens g*16..+15) ----
    int t0 = (blockIdx.x - 1024) * 32;
    const float4* Xv = (const float4*)(X + (size_t)t0 * 256);
    for (int n = tid; n < 2048; n += 256) {
      int row = n >> 6, sl = n & 63;
      ((float4*)xs[row])[sl] = Xv[row * 64 + sl];
    }
    __syncthreads();
    int j = tid & 127, grp = tid >> 7;
    float acc[16];
#pragma unroll
    for (int tt = 0; tt < 16; ++tt) acc[tt] = 0.f;
    for (int i4 = 0; i4 < 64; ++i4) {
      float4 w = Wi1P[i4 * 128 + j];
#pragma unroll
      for (int tt = 0; tt < 16; ++tt) {
        float4 x = ((const float4*)xs[grp * 16 + tt])[i4];
        acc[tt] += x.x * w.x + x.y * w.y + x.z * w.z + x.w * w.w;
      }
    }
    float b1 = bi1[j], w2 = Wi2[j];
    float p[16];
#pragma unroll
    for (int tt = 0; tt < 16; ++tt) {
      float hh = acc[tt] + b1;
      hh = hh > 0.f ? hh : 0.f;
      p[tt] = hh * w2;
    }
#pragma unroll
    for (int s = 1; s < 64; s <<= 1) {
#pragma unroll
      for (int tt = 0; tt < 16; ++tt) p[tt] += __shfl_xor(p[tt], s, 64);
    }
    int lane = tid & 63, wv_ = tid >> 6;
    if (lane == 0) {
#pragma unroll
      for (int tt = 0; tt < 16; ++tt) partial[wv_][tt] = p[tt];
    }
    __syncthreads();
    if (tid < 32) {
      int g = tid >> 4, tt = tid & 15;
      imp[t0 + g * 16 + tt] =
          partial[2 * g][tt] + partial[2 * g + 1][tt] + bi2[0];
    }
  }
}

// ---------- 2. top-6 select + Q projection (fused) + (block M_MSG) ranges ----------
__global__ __launch_bounds__(256) void topselq_kernel(
    const float* __restrict__ imp, const int* __restrict__ mb,
    const int* __restrict__ bidx, const float* __restrict__ X,
    const float4* __restrict__ WqP, const float* __restrict__ bq,
    int* __restrict__ selected, int* __restrict__ lo, int* __restrict__ hi,
    float* __restrict__ Qout) {
  int m = blockIdx.x;
  int tid = threadIdx.x;
  if (m == M_MSG) {  // fused ranges computation
    int g = tid;
    if (g < NBATCH) {
      int l = 0;
      while (l < M_MSG && bidx[l] < g) ++l;
      int h = l;
      while (h < M_MSG && bidx[h] == g) ++h;
      lo[g] = l * L_TOK;
      hi[g] = h * L_TOK;
    }
    return;
  }
  __shared__ int sel[KK];
  __shared__ float4 xs6[KK][64];  // 6 selected rows x 256 floats (full row)
  if (tid < 64) {  // wave 0: top-6 selection
    int l = tid;
    float myv = imp[m * 64 + l];
    int start = mb[2 * m];
    for (int k = 0; k < KK; ++k) {
      float rv = myv;
      int ri = l;
#pragma unroll
      for (int s = 1; s < 64; s <<= 1) {
        float ov = __shfl_xor(rv, s, 64);
        int oi = __shfl_xor(ri, s, 64);
        if (ov > rv || (ov == rv && oi < ri)) { rv = ov; ri = oi; }
      }
      if (l == 0) {
        selected[m * KK + k] = start + ri;
        sel[k] = start + ri;
      }
      if (l == ri) myv = -INFINITY;
    }
  }
  __syncthreads();
  for (int i = tid; i < KK * 64; i += 256) {  // stage full selected rows
    int r = i >> 6, d4 = i & 63;
    xs6[r][d4] = ((const float4*)X)[(size_t)sel[r] * 64 + d4];
  }
  __syncthreads();
  float acc[KK];
#pragma unroll
  for (int r = 0; r < KK; ++r) acc[r] = 0.f;
  for (int i4 = 0; i4 < 64; ++i4) {
    float4 w = WqP[i4 * 256 + tid];
#pragma unroll
    for (int r = 0; r < KK; ++r) {
      float4 x = xs6[r][i4];
      acc[r] += x.x * w.x + x.y * w.y + x.z * w.z + x.w * w.w;
    }
  }
  float bj = bq[tid];
#pragma unroll
  for (int r = 0; r < KK; ++r)
    Qout[(size_t)(m * KK + r) * 256 + tid] = (acc[r] + bj) * 0.125f;
}

// ---------- 5. scores + per-split top-10 (r14 structure, bf16 K) ----------
// block = (m, h, split): 2048 blocks, 128 threads = 2 waves.
// Wave w owns queries w*3+{0,1,2}; lane L owns key base+L of each 64-key
// chunk. K is bf16 packed dim-major Kb[h*8+d8][T] (uint4 = 8 dims): lane
// L's load is 64x16B contiguous -> 8 loads/chunk instead of 16 (duration
// tracked bytes-requested across r3/r5/r8/r10 variants; this halves them).
// Unpack bf16->fp32 is 1 VALU/dim; FMA count and the per-lane u64 top-10
// machinery are identical to r14. Q stays fp32 (only K is rounded).
__global__ __launch_bounds__(128) void scores_kernel(
    const float* __restrict__ Q, const unsigned* __restrict__ Kb,
    const int* __restrict__ lo_, const int* __restrict__ hi_,
    const int* __restrict__ bidx, unsigned long long* __restrict__ topk2) {
  int bid = blockIdx.x;
  // XCD swizzle: contiguous 256-block slab per XCD (bidx sorted).
  int sw = (bid & 7) * (M_MSG * NH * 2 / 8) + (bid >> 3);
  int m = sw >> 3;
  int h = (sw >> 1) & 3;
  int sp = sw & 1;
  int tid = threadIdx.x, lane = tid & 63, w = tid >> 6;
  int g = bidx[m];
  int lo = lo_[g], hi = hi_[g];
  int range = hi - lo;
  int n_all = (range + 63) >> 6;
  int n0 = (n_all + 1) >> 1;
  int nt = sp ? (n_all - n0) : n0;
  int start = lo + (sp ? n0 * 64 : 0);
  int end0 = lo + n0 * 64;
  int end = sp ? hi : (end0 < hi ? end0 : hi);

  __shared__ float4 qs4[KK][16];  // 6 queries x 64 dims (1.5 KB)
  const float4* Qv = (const float4*)Q;
  for (int i = tid; i < KK * 16; i += 128) {
    int qq = i >> 4, d4 = i & 15;
    qs4[qq][d4] = Qv[(size_t)(m * KK + qq) * 64 + h * 16 + d4];
  }
  __syncthreads();

  unsigned long long lst[3][KT];
#pragma unroll
  for (int j = 0; j < 3; ++j)
#pragma unroll
    for (int k = 0; k < KT; ++k) lst[j][k] = 0ULL;

  const uint4* Kh = (const uint4*)Kb + (size_t)h * 8 * T_TOK;

#pragma unroll 1
  for (int kb = 0; kb < nt; ++kb) {
    int t = start + kb * 64 + lane;
    int tc = t < hi ? t : hi - 1;
    uint4 kw[8];
#pragma unroll
    for (int d8 = 0; d8 < 8; ++d8) kw[d8] = Kh[(size_t)d8 * T_TOK + tc];
    float acc[3];
    acc[0] = 0.f; acc[1] = 0.f; acc[2] = 0.f;
#pragma unroll
    for (int d8 = 0; d8 < 8; ++d8) {
      float k0 = bflo(kw[d8].x), k1 = bfhi(kw[d8].x);
      float k2 = bflo(kw[d8].y), k3 = bfhi(kw[d8].y);
      float k4 = bflo(kw[d8].z), k5 = bfhi(kw[d8].z);
      float k6 = bflo(kw[d8].w), k7 = bfhi(kw[d8].w);
#pragma unroll
      for (int j = 0; j < 3; ++j) {
        float4 qa = qs4[w * 3 + j][d8 * 2];
        float4 qb = qs4[w * 3 + j][d8 * 2 + 1];
        acc[j] += k0 * qa.x + k1 * qa.y + k2 * qa.z + k3 * qa.w +
                  k4 * qb.x + k5 * qb.y + k6 * qb.z + k7 * qb.w;
      }
    }
    bool v0 = (t < end) && ((t >> 6) != m);
    unsigned nk = ~(unsigned)t;
#pragma unroll
    for (int j = 0; j < 3; ++j) {
      unsigned cc = v0 ? ordf(acc[j]) : 0u;
      unsigned long long key =
          cc ? (((unsigned long long)cc << 32) | nk) : 0ULL;
      if (key > lst[j][KT - 1]) {
        unsigned long long ins = key;
#pragma unroll
        for (int r = 0; r < KT; ++r) {
          unsigned long long cur = lst[j][r];
          unsigned long long mx = ins > cur ? ins : cur;
          unsigned long long mn = ins > cur ? cur : ins;
          lst[j][r] = mx;
          ins = mn;
        }
      }
    }
  }

  // ---- extraction merge across 64 lanes (3 queries interleaved for ILP) ----
  for (int k = 0; k < KT; ++k) {
    unsigned long long mx[3];
#pragma unroll
    for (int j = 0; j < 3; ++j) mx[j] = lst[j][0];
#pragma unroll
    for (int s_ = 1; s_ < 64; s_ <<= 1) {
#pragma unroll
      for (int j = 0; j < 3; ++j) {
        unsigned long long o = __shfl_xor(mx[j], s_, 64);
        if (o > mx[j]) mx[j] = o;
      }
    }
#pragma unroll
    for (int j = 0; j < 3; ++j) {
      if (mx[j] != 0ULL && lst[j][0] == mx[j]) {
#pragma unroll
        for (int r = 0; r < KT - 1; ++r) lst[j][r] = lst[j][r + 1];
        lst[j][KT - 1] = 0ULL;
      }
    }
    if (lane == 0) {
#pragma unroll
      for (int j = 0; j < 3; ++j) {
        int q = m * KK + w * 3 + j;
        topk2[((size_t)(q * NH + h) * 2 + sp) * KT + k] = mx[j];
      }
    }
  }
}

// ---------- 6. merge splits + softmax + gather V + Wo + scatter-add + avg ----------
__global__ __launch_bounds__(256) void finish_kernel(
    const unsigned long long* __restrict__ topk2, const float* __restrict__ V,
    const float4* __restrict__ WoP, const float* __restrict__ bo,
    const int* __restrict__ selected, float* __restrict__ out,
    float* __restrict__ out_avg) {
  int q0 = blockIdx.x * 16;
  int tid = threadIdx.x;
  __shared__ unsigned long long buf[64][2 * KT];  // 10 KB
  __shared__ float tvs[16][NH][KT];
  __shared__ int tis[16][NH][KT];
  __shared__ float wsm[16][NH * KT];
  __shared__ float att[16][256];
  // stage the 64 (q,h) pairs' split lists
  const unsigned long long* src = topk2 + (size_t)q0 * NH * 2 * KT;
  for (int i = tid; i < 64 * 2 * KT; i += 256) (&buf[0][0])[i] = src[i];
  __syncthreads();
  if (tid < 64) {
    int qq = tid >> 2, h = tid & 3;
    // two-pointer exact merge of the two sorted-desc lists + inline softmax
    int pa = 0, pb = 0;
    float e[KT];
    float m0 = 0.f, sum = 0.f;
#pragma unroll
    for (int k = 0; k < KT; ++k) {
      unsigned long long va = buf[tid][pa];
      unsigned long long vb = buf[tid][KT + pb];
      unsigned long long v;
      if (va >= vb) { v = va; ++pa; } else { v = vb; ++pb; }
      float scv;
      int t;
      if (v != 0ULL) {
        scv = unordf((unsigned)(v >> 32));
        t = (int)(~(unsigned)v);
      } else {
        scv = -1e30f;
        t = 0;
      }
      tvs[qq][h][k] = scv;
      tis[qq][h][k] = t;
      if (k == 0) m0 = scv;
      e[k] = expf(scv - m0);
      sum += e[k];
    }
    float inv = 1.f / sum;
#pragma unroll
    for (int k = 0; k < KT; ++k) wsm[qq][h * KT + k] = e[k] * inv;
  }
  __syncthreads();
  if (tid < 160) {
    int qq = tid / 10, k = tid % 10;
    out_avg[(size_t)(q0 + qq) * KT + k] =
        0.25f * (tvs[qq][0][k] + tvs[qq][1][k] + tvs[qq][2][k] + tvs[qq][3][k]);
  }
  int h = tid >> 6, d = tid & 63;
#pragma unroll 1
  for (int qq = 0; qq < 16; ++qq) {
    float a = 0.f;
#pragma unroll
    for (int k = 0; k < KT; ++k) {
      int t = tis[qq][h][k];
      a += wsm[qq][h * KT + k] * V[(size_t)t * 256 + h * 64 + d];
    }
    att[qq][tid] = a;
  }
  __syncthreads();
  float acc[16];
#pragma unroll
  for (int tt = 0; tt < 16; ++tt) acc[tt] = 0.f;
  for (int i4 = 0; i4 < 64; ++i4) {
    float4 wv = WoP[i4 * 256 + tid];  // coalesced panel load
#pragma unroll
    for (int tt = 0; tt < 16; ++tt) {
      float4 x = ((const float4*)att[tt])[i4];
      acc[tt] += x.x * wv.x + x.y * wv.y + x.z * wv.z + x.w * wv.w;
    }
  }
  float bj = bo[tid];
#pragma unroll 1
  for (int tt = 0; tt < 16; ++tt) {
    int s = selected[q0 + tt];
    out[(size_t)s * 256 + tid] += acc[tt] + bj;
  }
}

// ---------- launch ----------
extern "C" void kernel_launch(void* const* d_in, const int* in_sizes, int n_in,
                              void* d_out, int out_size, void* d_ws, size_t ws_size,
                              hipStream_t stream) {
  const float* X   = (const float*)d_in[0];
  const int*   mb  = (const int*)d_in[1];
  const int*   bidx= (const int*)d_in[2];
  const float* Wq  = (const float*)d_in[3];
  const float* bq  = (const float*)d_in[4];
  const float* Wk  = (const float*)d_in[5];
  const float* bk  = (const float*)d_in[6];
  const float* Wv  = (const float*)d_in[7];
  const float* bv  = (const float*)d_in[8];
  const float* Wi1 = (const float*)d_in[9];
  const float* bi1 = (const float*)d_in[10];
  const float* Wi2 = (const float*)d_in[11];
  const float* bi2 = (const float*)d_in[12];
  const float* Wo  = (const float*)d_in[13];
  const float* bo  = (const float*)d_in[14];

  float* out = (float*)d_out;
  float* out_avg = out + (size_t)T_TOK * D_HID;

  // K (bf16 packed, 8 MB) is staged in d_out's "updated" region
  // (dead until final memcpy+scatter).
  unsigned* Kmat = (unsigned*)out;

  char* ws = (char*)d_ws;
  size_t off = 0;
  float* V = (float*)(ws + off);        off += (size_t)T_TOK * 256 * 4;   // 16.78 MB
  float* Q = (float*)(ws + off);        off += (size_t)NQ * 256 * 4;      // 1.57 MB
  float* imp = (float*)(ws + off);      off += (size_t)T_TOK * 4;
  int* selected = (int*)(ws + off);     off += (size_t)NQ * 4;
  int* lo = (int*)(ws + off);           off += 64;
  int* hi = (int*)(ws + off);           off += 64;
  unsigned long long* topk2 = (unsigned long long*)(ws + off);
  off += (size_t)NQ * NH * 2 * KT * 8;                                    // 0.98 MB
  float4* WkP = (float4*)(ws + off);    off += (size_t)64 * 256 * 16;     // 256 KB
  float4* WvP = (float4*)(ws + off);    off += (size_t)64 * 256 * 16;
  float4* WqP = (float4*)(ws + off);    off += (size_t)64 * 256 * 16;
  float4* WoP = (float4*)(ws + off);    off += (size_t)64 * 256 * 16;
  float4* Wi1P = (float4*)(ws + off);   off += (size_t)64 * 128 * 16;     // 128 KB
  (void)ws_size; (void)in_sizes; (void)n_in; (void)out_size;

  wpanel_kernel<<<256, 64, 0, stream>>>(Wk, Wv, Wq, Wo, Wi1, WkP, WvP, WqP,
                                        WoP, Wi1P);
  kvimp_kernel<<<1536, 256, 0, stream>>>(X, WkP, bk, WvP, bv, Wi1P, bi1, Wi2,
                                         bi2, Kmat, V, imp);
  topselq_kernel<<<M_MSG + 1, 256, 0, stream>>>(imp, mb, bidx, X, WqP, bq,
                                                selected, lo, hi, Q);
  scores_kernel<<<M_MSG * NH * 2, 128, 0, stream>>>(Q, Kmat, lo, hi, bidx,
                                                    topk2);
  hipMemcpyAsync(out, X, (size_t)T_TOK * D_HID * sizeof(float),
                 hipMemcpyDeviceToDevice, stream);
  finish_kernel<<<NQ / 16, 256, 0, stream>>>(topk2, V, WoP, bo, selected, out,
                                             out_avg);
}

// Round 17
// 242.507 us; speedup vs baseline: 2.2250x; 1.2364x over previous
//
#include <hip/hip_runtime.h>
#include <math.h>

#define T_TOK 16384
#define M_MSG 256
#define L_TOK 64
#define KK 6
#define NQ (M_MSG * KK)   // 1536
#define D_HID 256
#define NH 4
#define HD 64
#define KT 10
#define NBATCH 8

// ---------- helpers ----------
__device__ __forceinline__ unsigned ordf(float f) {
  unsigned u = __float_as_uint(f);
  return (u & 0x80000000u) ? ~u : (u | 0x80000000u);
}
__device__ __forceinline__ float unordf(unsigned u) {
  return __uint_as_float((u & 0x80000000u) ? (u ^ 0x80000000u) : ~u);
}

typedef _Float16 h2v __attribute__((ext_vector_type(2)));
typedef __fp16 fp16x2 __attribute__((ext_vector_type(2)));  // cvt_pkrtz ret type
__device__ __forceinline__ h2v u2h(unsigned u) {
  return __builtin_bit_cast(h2v, u);
}
// pack two f32 -> f16x2 (RTZ; v_cvt_pkrtz_f16_f32, available all gfx9+)
__device__ __forceinline__ unsigned pkh(float a, float b) {
  fp16x2 h = __builtin_amdgcn_cvt_pkrtz(a, b);
  return __builtin_bit_cast(unsigned, h);
}
#if defined(__has_builtin) && __has_builtin(__builtin_amdgcn_fdot2)
__device__ __forceinline__ float FDOT2(h2v a, h2v b, float c) {
  return __builtin_amdgcn_fdot2(a, b, c, false);  // v_dot2_f32_f16: 2 MACs
}
#else
__device__ __forceinline__ float FDOT2(h2v a, h2v b, float c) {
  return c + (float)a.x * (float)b.x + (float)a.y * (float)b.y;
}
#endif

// ---------- 0. weight k-panel transpose ----------
__global__ __launch_bounds__(64) void wpanel_kernel(
    const float* __restrict__ Wk, const float* __restrict__ Wv,
    const float* __restrict__ Wq, const float* __restrict__ Wo,
    const float* __restrict__ Wi1, float4* __restrict__ WkP,
    float4* __restrict__ WvP, float4* __restrict__ WqP,
    float4* __restrict__ WoP, float4* __restrict__ Wi1P) {
  int c = blockIdx.x;    // 0..255 (column)
  int k4 = threadIdx.x;  // 0..63 (dim group)
  WkP[k4 * 256 + c] = ((const float4*)(Wk + (size_t)c * 256))[k4];
  WvP[k4 * 256 + c] = ((const float4*)(Wv + (size_t)c * 256))[k4];
  WqP[k4 * 256 + c] = ((const float4*)(Wq + (size_t)c * 256))[k4];
  WoP[k4 * 256 + c] = ((const float4*)(Wo + (size_t)c * 256))[k4];
  if (c < 128) Wi1P[k4 * 128 + c] = ((const float4*)(Wi1 + (size_t)c * 256))[k4];
}

// ---------- 1. fused KV-projection + importance MLP ----------
// K output: f16 packed dim-major Kb[h*8+d8][t] = uint4 holding dims
// d8*8..d8*8+7 of token t (RTZ). V stays fp32 row-major.
__global__ __launch_bounds__(256) void kvimp_kernel(
    const float* __restrict__ X, const float4* __restrict__ WkP,
    const float* __restrict__ bk, const float4* __restrict__ WvP,
    const float* __restrict__ bv, const float4* __restrict__ Wi1P,
    const float* __restrict__ bi1, const float* __restrict__ Wi2,
    const float* __restrict__ bi2, unsigned* __restrict__ Kout,
    float* __restrict__ Vout, float* __restrict__ imp) {
  __shared__ float xs[32][260];  // +4 pad: KV transpose reads spread banks
  __shared__ float partial[4][16];
  int tid = threadIdx.x;
  if (blockIdx.x < 1024) {
    // ---- KV path (16 rows) ----
    int r0 = blockIdx.x * 16;
    const float4* Xv = (const float4*)(X + (size_t)r0 * 256);
    for (int n = tid; n < 1024; n += 256) {
      int row = n >> 6, sl = n & 63;
      ((float4*)xs[row])[sl] = Xv[row * 64 + sl];
    }
    __syncthreads();
    float ak[16], av[16];
#pragma unroll
    for (int tt = 0; tt < 16; ++tt) { ak[tt] = 0.f; av[tt] = 0.f; }
    for (int i4 = 0; i4 < 64; ++i4) {
      float4 wk = WkP[i4 * 256 + tid];  // coalesced panel loads
      float4 wv = WvP[i4 * 256 + tid];
#pragma unroll
      for (int tt = 0; tt < 16; ++tt) {
        float4 x = ((const float4*)xs[tt])[i4];
        ak[tt] += x.x * wk.x + x.y * wk.y + x.z * wk.z + x.w * wk.w;
        av[tt] += x.x * wv.x + x.y * wv.y + x.z * wv.z + x.w * wv.w;
      }
    }
    float bkj = bk[tid], bvj = bv[tid];
#pragma unroll 1
    for (int tt = 0; tt < 16; ++tt)
      Vout[(size_t)(r0 + tt) * 256 + tid] = av[tt] + bvj;
    __syncthreads();  // all FMA reads of xs done
#pragma unroll
    for (int tt = 0; tt < 16; ++tt) xs[tt][tid] = ak[tt] + bkj;
    __syncthreads();
    uint4* Kbv = (uint4*)Kout;
#pragma unroll
    for (int i = 0; i < 2; ++i) {
      int idx = i * 256 + tid;    // 0..511
      int hd8 = idx >> 4;         // 0..31 (h*8 + d8)
      int r = idx & 15;
      const float* row = &xs[r][hd8 * 8];
      uint4 p;
      p.x = pkh(row[0], row[1]);
      p.y = pkh(row[2], row[3]);
      p.z = pkh(row[4], row[5]);
      p.w = pkh(row[6], row[7]);
      Kbv[(size_t)hd8 * T_TOK + r0 + r] = p;
    }
  } else {
    // ---- imp path (32 tokens; grp g = tid>>7 owns tokens g*16..+15) ----
    int t0 = (blockIdx.x - 1024) * 32;
    const float4* Xv = (const float4*)(X + (size_t)t0 * 256);
    for (int n = tid; n < 2048; n += 256) {
      int row = n >> 6, sl = n & 63;
      ((float4*)xs[row])[sl] = Xv[row * 64 + sl];
    }
    __syncthreads();
    int j = tid & 127, grp = tid >> 7;
    float acc[16];
#pragma unroll
    for (int tt = 0; tt < 16; ++tt) acc[tt] = 0.f;
    for (int i4 = 0; i4 < 64; ++i4) {
      float4 w = Wi1P[i4 * 128 + j];
#pragma unroll
      for (int tt = 0; tt < 16; ++tt) {
        float4 x = ((const float4*)xs[grp * 16 + tt])[i4];
        acc[tt] += x.x * w.x + x.y * w.y + x.z * w.z + x.w * w.w;
      }
    }
    float b1 = bi1[j], w2 = Wi2[j];
    float p[16];
#pragma unroll
    for (int tt = 0; tt < 16; ++tt) {
      float hh = acc[tt] + b1;
      hh = hh > 0.f ? hh : 0.f;
      p[tt] = hh * w2;
    }
#pragma unroll
    for (int s = 1; s < 64; s <<= 1) {
#pragma unroll
      for (int tt = 0; tt < 16; ++tt) p[tt] += __shfl_xor(p[tt], s, 64);
    }
    int lane = tid & 63, wv_ = tid >> 6;
    if (lane == 0) {
#pragma unroll
      for (int tt = 0; tt < 16; ++tt) partial[wv_][tt] = p[tt];
    }
    __syncthreads();
    if (tid < 32) {
      int g = tid >> 4, tt = tid & 15;
      imp[t0 + g * 16 + tt] =
          partial[2 * g][tt] + partial[2 * g + 1][tt] + bi2[0];
    }
  }
}

// ---------- 2. top-6 select + Q projection (fused) + (block M_MSG) ranges ----------
__global__ __launch_bounds__(256) void topselq_kernel(
    const float* __restrict__ imp, const int* __restrict__ mb,
    const int* __restrict__ bidx, const float* __restrict__ X,
    const float4* __restrict__ WqP, const float* __restrict__ bq,
    int* __restrict__ selected, int* __restrict__ lo, int* __restrict__ hi,
    float* __restrict__ Qout) {
  int m = blockIdx.x;
  int tid = threadIdx.x;
  if (m == M_MSG) {  // fused ranges computation
    int g = tid;
    if (g < NBATCH) {
      int l = 0;
      while (l < M_MSG && bidx[l] < g) ++l;
      int h = l;
      while (h < M_MSG && bidx[h] == g) ++h;
      lo[g] = l * L_TOK;
      hi[g] = h * L_TOK;
    }
    return;
  }
  __shared__ int sel[KK];
  __shared__ float4 xs6[KK][64];  // 6 selected rows x 256 floats (full row)
  if (tid < 64) {  // wave 0: top-6 selection
    int l = tid;
    float myv = imp[m * 64 + l];
    int start = mb[2 * m];
    for (int k = 0; k < KK; ++k) {
      float rv = myv;
      int ri = l;
#pragma unroll
      for (int s = 1; s < 64; s <<= 1) {
        float ov = __shfl_xor(rv, s, 64);
        int oi = __shfl_xor(ri, s, 64);
        if (ov > rv || (ov == rv && oi < ri)) { rv = ov; ri = oi; }
      }
      if (l == 0) {
        selected[m * KK + k] = start + ri;
        sel[k] = start + ri;
      }
      if (l == ri) myv = -INFINITY;
    }
  }
  __syncthreads();
  for (int i = tid; i < KK * 64; i += 256) {  // stage full selected rows
    int r = i >> 6, d4 = i & 63;
    xs6[r][d4] = ((const float4*)X)[(size_t)sel[r] * 64 + d4];
  }
  __syncthreads();
  float acc[KK];
#pragma unroll
  for (int r = 0; r < KK; ++r) acc[r] = 0.f;
  for (int i4 = 0; i4 < 64; ++i4) {
    float4 w = WqP[i4 * 256 + tid];
#pragma unroll
    for (int r = 0; r < KK; ++r) {
      float4 x = xs6[r][i4];
      acc[r] += x.x * w.x + x.y * w.y + x.z * w.z + x.w * w.w;
    }
  }
  float bj = bq[tid];
#pragma unroll
  for (int r = 0; r < KK; ++r)
    Qout[(size_t)(m * KK + r) * 256 + tid] = (acc[r] + bj) * 0.125f;
}

// ---------- 5. scores + per-split top-10 (r14 structure, f16 K/Q + dot2) ----------
// block = (m, h, split): 2048 blocks, 128 threads = 2 waves.
// Wave w owns queries w*3+{0,1,2}; lane L owns key base+L of each 64-key
// chunk. K is f16 packed dim-major Kb[h*8+d8][T] (uint4 = 8 dims): 8 loads
// per chunk (64x16B contiguous). Q converted to packed f16 once at stage
// (LDS 768 B; 24 ds_read_b128/chunk vs 48). Inner loop = v_dot2_f32_f16
// (2 MACs/instr, no unpack): ~96 dot2 + select per chunk vs r15's ~300
// VALU ops (64 bf16-unpack + 192 scalar FMA). f16 (10-bit mantissa) is
// ~4x more accurate than r15's bf16, so absmax should IMPROVE. Selection
// machinery identical to r14/r15.
__global__ __launch_bounds__(128) void scores_kernel(
    const float* __restrict__ Q, const unsigned* __restrict__ Kb,
    const int* __restrict__ lo_, const int* __restrict__ hi_,
    const int* __restrict__ bidx, unsigned long long* __restrict__ topk2) {
  int bid = blockIdx.x;
  // XCD swizzle: contiguous 256-block slab per XCD (bidx sorted).
  int sw = (bid & 7) * (M_MSG * NH * 2 / 8) + (bid >> 3);
  int m = sw >> 3;
  int h = (sw >> 1) & 3;
  int sp = sw & 1;
  int tid = threadIdx.x, lane = tid & 63, w = tid >> 6;
  int g = bidx[m];
  int lo = lo_[g], hi = hi_[g];
  int range = hi - lo;
  int n_all = (range + 63) >> 6;
  int n0 = (n_all + 1) >> 1;
  int nt = sp ? (n_all - n0) : n0;
  int start = lo + (sp ? n0 * 64 : 0);
  int end0 = lo + n0 * 64;
  int end = sp ? hi : (end0 < hi ? end0 : hi);

  __shared__ uint4 qh[KK][8];  // 6 queries x 64 dims f16-packed (768 B)
  const float4* Qv = (const float4*)Q;
  for (int i = tid; i < KK * 8; i += 128) {
    int qq = i >> 3, d8 = i & 7;
    float4 a = Qv[(size_t)(m * KK + qq) * 64 + h * 16 + d8 * 2];
    float4 b = Qv[(size_t)(m * KK + qq) * 64 + h * 16 + d8 * 2 + 1];
    uint4 p;
    p.x = pkh(a.x, a.y);
    p.y = pkh(a.z, a.w);
    p.z = pkh(b.x, b.y);
    p.w = pkh(b.z, b.w);
    qh[qq][d8] = p;
  }
  __syncthreads();

  unsigned long long lst[3][KT];
#pragma unroll
  for (int j = 0; j < 3; ++j)
#pragma unroll
    for (int k = 0; k < KT; ++k) lst[j][k] = 0ULL;

  const uint4* Kh = (const uint4*)Kb + (size_t)h * 8 * T_TOK;

#pragma unroll 1
  for (int kb = 0; kb < nt; ++kb) {
    int t = start + kb * 64 + lane;
    int tc = t < hi ? t : hi - 1;
    uint4 kw[8];
#pragma unroll
    for (int d8 = 0; d8 < 8; ++d8) kw[d8] = Kh[(size_t)d8 * T_TOK + tc];
    float acc[3];
    acc[0] = 0.f; acc[1] = 0.f; acc[2] = 0.f;
#pragma unroll
    for (int d8 = 0; d8 < 8; ++d8) {
      uint4 kv = kw[d8];
#pragma unroll
      for (int j = 0; j < 3; ++j) {
        uint4 qv = qh[w * 3 + j][d8];
        float a = acc[j];
        a = FDOT2(u2h(kv.x), u2h(qv.x), a);
        a = FDOT2(u2h(kv.y), u2h(qv.y), a);
        a = FDOT2(u2h(kv.z), u2h(qv.z), a);
        a = FDOT2(u2h(kv.w), u2h(qv.w), a);
        acc[j] = a;
      }
    }
    bool v0 = (t < end) && ((t >> 6) != m);
    unsigned nk = ~(unsigned)t;
#pragma unroll
    for (int j = 0; j < 3; ++j) {
      unsigned cc = v0 ? ordf(acc[j]) : 0u;
      unsigned long long key =
          cc ? (((unsigned long long)cc << 32) | nk) : 0ULL;
      if (key > lst[j][KT - 1]) {
        unsigned long long ins = key;
#pragma unroll
        for (int r = 0; r < KT; ++r) {
          unsigned long long cur = lst[j][r];
          unsigned long long mx = ins > cur ? ins : cur;
          unsigned long long mn = ins > cur ? cur : ins;
          lst[j][r] = mx;
          ins = mn;
        }
      }
    }
  }

  // ---- extraction merge across 64 lanes (3 queries interleaved for ILP) ----
  for (int k = 0; k < KT; ++k) {
    unsigned long long mx[3];
#pragma unroll
    for (int j = 0; j < 3; ++j) mx[j] = lst[j][0];
#pragma unroll
    for (int s_ = 1; s_ < 64; s_ <<= 1) {
#pragma unroll
      for (int j = 0; j < 3; ++j) {
        unsigned long long o = __shfl_xor(mx[j], s_, 64);
        if (o > mx[j]) mx[j] = o;
      }
    }
#pragma unroll
    for (int j = 0; j < 3; ++j) {
      if (mx[j] != 0ULL && lst[j][0] == mx[j]) {
#pragma unroll
        for (int r = 0; r < KT - 1; ++r) lst[j][r] = lst[j][r + 1];
        lst[j][KT - 1] = 0ULL;
      }
    }
    if (lane == 0) {
#pragma unroll
      for (int j = 0; j < 3; ++j) {
        int q = m * KK + w * 3 + j;
        topk2[((size_t)(q * NH + h) * 2 + sp) * KT + k] = mx[j];
      }
    }
  }
}

// ---------- 6. merge splits + softmax + gather V + Wo + scatter-add + avg ----------
__global__ __launch_bounds__(256) void finish_kernel(
    const unsigned long long* __restrict__ topk2, const float* __restrict__ V,
    const float4* __restrict__ WoP, const float* __restrict__ bo,
    const int* __restrict__ selected, float* __restrict__ out,
    float* __restrict__ out_avg) {
  int q0 = blockIdx.x * 16;
  int tid = threadIdx.x;
  __shared__ unsigned long long buf[64][2 * KT];  // 10 KB
  __shared__ float tvs[16][NH][KT];
  __shared__ int tis[16][NH][KT];
  __shared__ float wsm[16][NH * KT];
  __shared__ float att[16][256];
  // stage the 64 (q,h) pairs' split lists
  const unsigned long long* src = topk2 + (size_t)q0 * NH * 2 * KT;
  for (int i = tid; i < 64 * 2 * KT; i += 256) (&buf[0][0])[i] = src[i];
  __syncthreads();
  if (tid < 64) {
    int qq = tid >> 2, h = tid & 3;
    // two-pointer exact merge of the two sorted-desc lists + inline softmax
    int pa = 0, pb = 0;
    float e[KT];
    float m0 = 0.f, sum = 0.f;
#pragma unroll
    for (int k = 0; k < KT; ++k) {
      unsigned long long va = buf[tid][pa];
      unsigned long long vb = buf[tid][KT + pb];
      unsigned long long v;
      if (va >= vb) { v = va; ++pa; } else { v = vb; ++pb; }
      float scv;
      int t;
      if (v != 0ULL) {
        scv = unordf((unsigned)(v >> 32));
        t = (int)(~(unsigned)v);
      } else {
        scv = -1e30f;
        t = 0;
      }
      tvs[qq][h][k] = scv;
      tis[qq][h][k] = t;
      if (k == 0) m0 = scv;
      e[k] = expf(scv - m0);
      sum += e[k];
    }
    float inv = 1.f / sum;
#pragma unroll
    for (int k = 0; k < KT; ++k) wsm[qq][h * KT + k] = e[k] * inv;
  }
  __syncthreads();
  if (tid < 160) {
    int qq = tid / 10, k = tid % 10;
    out_avg[(size_t)(q0 + qq) * KT + k] =
        0.25f * (tvs[qq][0][k] + tvs[qq][1][k] + tvs[qq][2][k] + tvs[qq][3][k]);
  }
  int h = tid >> 6, d = tid & 63;
#pragma unroll 1
  for (int qq = 0; qq < 16; ++qq) {
    float a = 0.f;
#pragma unroll
    for (int k = 0; k < KT; ++k) {
      int t = tis[qq][h][k];
      a += wsm[qq][h * KT + k] * V[(size_t)t * 256 + h * 64 + d];
    }
    att[qq][tid] = a;
  }
  __syncthreads();
  float acc[16];
#pragma unroll
  for (int tt = 0; tt < 16; ++tt) acc[tt] = 0.f;
  for (int i4 = 0; i4 < 64; ++i4) {
    float4 wv = WoP[i4 * 256 + tid];  // coalesced panel load
#pragma unroll
    for (int tt = 0; tt < 16; ++tt) {
      float4 x = ((const float4*)att[tt])[i4];
      acc[tt] += x.x * wv.x + x.y * wv.y + x.z * wv.z + x.w * wv.w;
    }
  }
  float bj = bo[tid];
#pragma unroll 1
  for (int tt = 0; tt < 16; ++tt) {
    int s = selected[q0 + tt];
    out[(size_t)s * 256 + tid] += acc[tt] + bj;
  }
}

// ---------- launch ----------
extern "C" void kernel_launch(void* const* d_in, const int* in_sizes, int n_in,
                              void* d_out, int out_size, void* d_ws, size_t ws_size,
                              hipStream_t stream) {
  const float* X   = (const float*)d_in[0];
  const int*   mb  = (const int*)d_in[1];
  const int*   bidx= (const int*)d_in[2];
  const float* Wq  = (const float*)d_in[3];
  const float* bq  = (const float*)d_in[4];
  const float* Wk  = (const float*)d_in[5];
  const float* bk  = (const float*)d_in[6];
  const float* Wv  = (const float*)d_in[7];
  const float* bv  = (const float*)d_in[8];
  const float* Wi1 = (const float*)d_in[9];
  const float* bi1 = (const float*)d_in[10];
  const float* Wi2 = (const float*)d_in[11];
  const float* bi2 = (const float*)d_in[12];
  const float* Wo  = (const float*)d_in[13];
  const float* bo  = (const float*)d_in[14];

  float* out = (float*)d_out;
  float* out_avg = out + (size_t)T_TOK * D_HID;

  // K (f16 packed, 8 MB) is staged in d_out's "updated" region
  // (dead until final memcpy+scatter).
  unsigned* Kmat = (unsigned*)out;

  char* ws = (char*)d_ws;
  size_t off = 0;
  float* V = (float*)(ws + off);        off += (size_t)T_TOK * 256 * 4;   // 16.78 MB
  float* Q = (float*)(ws + off);        off += (size_t)NQ * 256 * 4;      // 1.57 MB
  float* imp = (float*)(ws + off);      off += (size_t)T_TOK * 4;
  int* selected = (int*)(ws + off);     off += (size_t)NQ * 4;
  int* lo = (int*)(ws + off);           off += 64;
  int* hi = (int*)(ws + off);           off += 64;
  unsigned long long* topk2 = (unsigned long long*)(ws + off);
  off += (size_t)NQ * NH * 2 * KT * 8;                                    // 0.98 MB
  float4* WkP = (float4*)(ws + off);    off += (size_t)64 * 256 * 16;     // 256 KB
  float4* WvP = (float4*)(ws + off);    off += (size_t)64 * 256 * 16;
  float4* WqP = (float4*)(ws + off);    off += (size_t)64 * 256 * 16;
  float4* WoP = (float4*)(ws + off);    off += (size_t)64 * 256 * 16;
  float4* Wi1P = (float4*)(ws + off);   off += (size_t)64 * 128 * 16;     // 128 KB
  (void)ws_size; (void)in_sizes; (void)n_in; (void)out_size;

  wpanel_kernel<<<256, 64, 0, stream>>>(Wk, Wv, Wq, Wo, Wi1, WkP, WvP, WqP,
                                        WoP, Wi1P);
  kvimp_kernel<<<1536, 256, 0, stream>>>(X, WkP, bk, WvP, bv, Wi1P, bi1, Wi2,
                                         bi2, Kmat, V, imp);
  topselq_kernel<<<M_MSG + 1, 256, 0, stream>>>(imp, mb, bidx, X, WqP, bq,
                                                selected, lo, hi, Q);
  scores_kernel<<<M_MSG * NH * 2, 128, 0, stream>>>(Q, Kmat, lo, hi, bidx,
                                                    topk2);
  hipMemcpyAsync(out, X, (size_t)T_TOK * D_HID * sizeof(float),
                 hipMemcpyDeviceToDevice, stream);
  finish_kernel<<<NQ / 16, 256, 0, stream>>>(topk2, V, WoP, bo, selected, out,
                                             out_avg);
}

// Round 18
// 210.340 us; speedup vs baseline: 2.5652x; 1.1529x over previous
//
#include <hip/hip_runtime.h>
#include <math.h>

#define T_TOK 16384
#define M_MSG 256
#define L_TOK 64
#define KK 6
#define NQ (M_MSG * KK)   // 1536
#define D_HID 256
#define NH 4
#define HD 64
#define KT 10
#define NBATCH 8

// ---------- helpers ----------
__device__ __forceinline__ unsigned ordf(float f) {
  unsigned u = __float_as_uint(f);
  return (u & 0x80000000u) ? ~u : (u | 0x80000000u);
}
__device__ __forceinline__ float unordf(unsigned u) {
  return __uint_as_float((u & 0x80000000u) ? (u ^ 0x80000000u) : ~u);
}

typedef _Float16 h2v __attribute__((ext_vector_type(2)));
typedef __fp16 fp16x2 __attribute__((ext_vector_type(2)));  // cvt_pkrtz ret type
__device__ __forceinline__ h2v u2h(unsigned u) {
  return __builtin_bit_cast(h2v, u);
}
// pack two f32 -> f16x2 (RTZ; v_cvt_pkrtz_f16_f32, available all gfx9+)
__device__ __forceinline__ unsigned pkh(float a, float b) {
  fp16x2 h = __builtin_amdgcn_cvt_pkrtz(a, b);
  return __builtin_bit_cast(unsigned, h);
}
#if defined(__has_builtin) && __has_builtin(__builtin_amdgcn_fdot2)
__device__ __forceinline__ float FDOT2(h2v a, h2v b, float c) {
  return __builtin_amdgcn_fdot2(a, b, c, false);  // v_dot2_f32_f16: 2 MACs
}
#else
__device__ __forceinline__ float FDOT2(h2v a, h2v b, float c) {
  return c + (float)a.x * (float)b.x + (float)a.y * (float)b.y;
}
#endif

// ---------- 0. weight panel transpose ----------
// WqP/WoP/Wi1P: f32 k-panels (coalesced float4 per column).
// WkH/WvH: f16-packed dim-major panels WH[d8*256+c] = uint4 of dims
// d8*8..d8*8+7 of column c (feeds the dot2 projection inner loop).
__global__ __launch_bounds__(64) void wpanel_kernel(
    const float* __restrict__ Wk, const float* __restrict__ Wv,
    const float* __restrict__ Wq, const float* __restrict__ Wo,
    const float* __restrict__ Wi1, uint4* __restrict__ WkH,
    uint4* __restrict__ WvH, float4* __restrict__ WqP,
    float4* __restrict__ WoP, float4* __restrict__ Wi1P) {
  int c = blockIdx.x;    // 0..255 (column)
  int t = threadIdx.x;   // 0..63
  WqP[t * 256 + c] = ((const float4*)(Wq + (size_t)c * 256))[t];
  WoP[t * 256 + c] = ((const float4*)(Wo + (size_t)c * 256))[t];
  if (c < 128) Wi1P[t * 128 + c] = ((const float4*)(Wi1 + (size_t)c * 256))[t];
  const float* Wsrc = (t < 32) ? Wk : Wv;
  uint4* dst = (t < 32) ? WkH : WvH;
  int d8 = t & 31;
  float4 a = ((const float4*)(Wsrc + (size_t)c * 256))[d8 * 2];
  float4 b = ((const float4*)(Wsrc + (size_t)c * 256))[d8 * 2 + 1];
  uint4 p;
  p.x = pkh(a.x, a.y);
  p.y = pkh(a.z, a.w);
  p.z = pkh(b.x, b.y);
  p.w = pkh(b.z, b.w);
  dst[d8 * 256 + c] = p;
}

// ---------- 1. fused KV-projection (f16 dot2) + importance MLP (f32) ----------
// KV path: X tile packed to f16 in LDS (u32 view of xs, [16][132] u32 rows);
// inner loop = v_dot2_f32_f16 (fp32 accum), HALF the VALU instrs of the
// scalar-fp32 version (r17's 112us was pure FMA-issue time). K stored f16
// packed dim-major Kb[h*8+d8][t]; V fp32 row-major. imp path untouched
// (fp32 exact -- importance flips would change WHICH rows are selected).
__global__ __launch_bounds__(256) void kvimp_kernel(
    const float* __restrict__ X, const uint4* __restrict__ WkH,
    const float* __restrict__ bk, const uint4* __restrict__ WvH,
    const float* __restrict__ bv, const float4* __restrict__ Wi1P,
    const float* __restrict__ bi1, const float* __restrict__ Wi2,
    const float* __restrict__ bi2, unsigned* __restrict__ Kout,
    float* __restrict__ Vout, float* __restrict__ imp) {
  __shared__ float xs[32][260];  // KV path reuses rows 0..15 as u32 view
  __shared__ float partial[4][16];
  int tid = threadIdx.x;
  if (blockIdx.x < 1024) {
    // ---- KV path (16 rows, f16 dot2) ----
    int r0 = blockIdx.x * 16;
    unsigned* xh = (unsigned*)&xs[0][0];  // [16][132] u32 (row = 528 B)
    const float4* Xv = (const float4*)(X + (size_t)r0 * 256);
#pragma unroll
    for (int i = 0; i < 2; ++i) {
      int n = i * 256 + tid;   // 0..511
      int row = n >> 5, d8 = n & 31;
      float4 a = Xv[row * 64 + d8 * 2];
      float4 b = Xv[row * 64 + d8 * 2 + 1];
      uint4 p;
      p.x = pkh(a.x, a.y);
      p.y = pkh(a.z, a.w);
      p.z = pkh(b.x, b.y);
      p.w = pkh(b.z, b.w);
      ((uint4*)(xh + row * 132))[d8] = p;
    }
    __syncthreads();
    float ak[16], av[16];
#pragma unroll
    for (int tt = 0; tt < 16; ++tt) { ak[tt] = 0.f; av[tt] = 0.f; }
    for (int d8 = 0; d8 < 32; ++d8) {
      uint4 wk = WkH[d8 * 256 + tid];  // coalesced f16 panel loads
      uint4 wv = WvH[d8 * 256 + tid];
#pragma unroll
      for (int tt = 0; tt < 16; ++tt) {
        uint4 xv = ((const uint4*)(xh + tt * 132))[d8];  // broadcast
        float a = ak[tt];
        a = FDOT2(u2h(xv.x), u2h(wk.x), a);
        a = FDOT2(u2h(xv.y), u2h(wk.y), a);
        a = FDOT2(u2h(xv.z), u2h(wk.z), a);
        a = FDOT2(u2h(xv.w), u2h(wk.w), a);
        ak[tt] = a;
        float v = av[tt];
        v = FDOT2(u2h(xv.x), u2h(wv.x), v);
        v = FDOT2(u2h(xv.y), u2h(wv.y), v);
        v = FDOT2(u2h(xv.z), u2h(wv.z), v);
        v = FDOT2(u2h(xv.w), u2h(wv.w), v);
        av[tt] = v;
      }
    }
    float bkj = bk[tid], bvj = bv[tid];
#pragma unroll 1
    for (int tt = 0; tt < 16; ++tt)
      Vout[(size_t)(r0 + tt) * 256 + tid] = av[tt] + bvj;
    __syncthreads();  // all reads of xh done
#pragma unroll
    for (int tt = 0; tt < 16; ++tt) xs[tt][tid] = ak[tt] + bkj;
    __syncthreads();
    uint4* Kbv = (uint4*)Kout;
#pragma unroll
    for (int i = 0; i < 2; ++i) {
      int idx = i * 256 + tid;    // 0..511
      int hd8 = idx >> 4;         // 0..31 (h*8 + d8)
      int r = idx & 15;
      const float* row = &xs[r][hd8 * 8];
      uint4 p;
      p.x = pkh(row[0], row[1]);
      p.y = pkh(row[2], row[3]);
      p.z = pkh(row[4], row[5]);
      p.w = pkh(row[6], row[7]);
      Kbv[(size_t)hd8 * T_TOK + r0 + r] = p;
    }
  } else {
    // ---- imp path (32 tokens; grp g = tid>>7 owns tokens g*16..+15) ----
    int t0 = (blockIdx.x - 1024) * 32;
    const float4* Xv = (const float4*)(X + (size_t)t0 * 256);
    for (int n = tid; n < 2048; n += 256) {
      int row = n >> 6, sl = n & 63;
      ((float4*)xs[row])[sl] = Xv[row * 64 + sl];
    }
    __syncthreads();
    int j = tid & 127, grp = tid >> 7;
    float acc[16];
#pragma unroll
    for (int tt = 0; tt < 16; ++tt) acc[tt] = 0.f;
    for (int i4 = 0; i4 < 64; ++i4) {
      float4 w = Wi1P[i4 * 128 + j];
#pragma unroll
      for (int tt = 0; tt < 16; ++tt) {
        float4 x = ((const float4*)xs[grp * 16 + tt])[i4];
        acc[tt] += x.x * w.x + x.y * w.y + x.z * w.z + x.w * w.w;
      }
    }
    float b1 = bi1[j], w2 = Wi2[j];
    float p[16];
#pragma unroll
    for (int tt = 0; tt < 16; ++tt) {
      float hh = acc[tt] + b1;
      hh = hh > 0.f ? hh : 0.f;
      p[tt] = hh * w2;
    }
#pragma unroll
    for (int s = 1; s < 64; s <<= 1) {
#pragma unroll
      for (int tt = 0; tt < 16; ++tt) p[tt] += __shfl_xor(p[tt], s, 64);
    }
    int lane = tid & 63, wv_ = tid >> 6;
    if (lane == 0) {
#pragma unroll
      for (int tt = 0; tt < 16; ++tt) partial[wv_][tt] = p[tt];
    }
    __syncthreads();
    if (tid < 32) {
      int g = tid >> 4, tt = tid & 15;
      imp[t0 + g * 16 + tt] =
          partial[2 * g][tt] + partial[2 * g + 1][tt] + bi2[0];
    }
  }
}

// ---------- 2. top-6 select + Q projection (fused) + (block M_MSG) ranges ----------
__global__ __launch_bounds__(256) void topselq_kernel(
    const float* __restrict__ imp, const int* __restrict__ mb,
    const int* __restrict__ bidx, const float* __restrict__ X,
    const float4* __restrict__ WqP, const float* __restrict__ bq,
    int* __restrict__ selected, int* __restrict__ lo, int* __restrict__ hi,
    float* __restrict__ Qout) {
  int m = blockIdx.x;
  int tid = threadIdx.x;
  if (m == M_MSG) {  // fused ranges computation
    int g = tid;
    if (g < NBATCH) {
      int l = 0;
      while (l < M_MSG && bidx[l] < g) ++l;
      int h = l;
      while (h < M_MSG && bidx[h] == g) ++h;
      lo[g] = l * L_TOK;
      hi[g] = h * L_TOK;
    }
    return;
  }
  __shared__ int sel[KK];
  __shared__ float4 xs6[KK][64];  // 6 selected rows x 256 floats (full row)
  if (tid < 64) {  // wave 0: top-6 selection
    int l = tid;
    float myv = imp[m * 64 + l];
    int start = mb[2 * m];
    for (int k = 0; k < KK; ++k) {
      float rv = myv;
      int ri = l;
#pragma unroll
      for (int s = 1; s < 64; s <<= 1) {
        float ov = __shfl_xor(rv, s, 64);
        int oi = __shfl_xor(ri, s, 64);
        if (ov > rv || (ov == rv && oi < ri)) { rv = ov; ri = oi; }
      }
      if (l == 0) {
        selected[m * KK + k] = start + ri;
        sel[k] = start + ri;
      }
      if (l == ri) myv = -INFINITY;
    }
  }
  __syncthreads();
  for (int i = tid; i < KK * 64; i += 256) {  // stage full selected rows
    int r = i >> 6, d4 = i & 63;
    xs6[r][d4] = ((const float4*)X)[(size_t)sel[r] * 64 + d4];
  }
  __syncthreads();
  float acc[KK];
#pragma unroll
  for (int r = 0; r < KK; ++r) acc[r] = 0.f;
  for (int i4 = 0; i4 < 64; ++i4) {
    float4 w = WqP[i4 * 256 + tid];
#pragma unroll
    for (int r = 0; r < KK; ++r) {
      float4 x = xs6[r][i4];
      acc[r] += x.x * w.x + x.y * w.y + x.z * w.z + x.w * w.w;
    }
  }
  float bj = bq[tid];
#pragma unroll
  for (int r = 0; r < KK; ++r)
    Qout[(size_t)(m * KK + r) * 256 + tid] = (acc[r] + bj) * 0.125f;
}

// ---------- 5. scores + per-split top-10 (f16 K/Q + dot2) ----------
// block = (m, h, split): 2048 blocks, 128 threads = 2 waves.
// Wave w owns queries w*3+{0,1,2}; lane L owns key base+L of each 64-key
// chunk. K f16 packed dim-major Kb[h*8+d8][T]: 8 coalesced loads/chunk.
// Q packed f16 at stage. Inner loop = v_dot2_f32_f16. Per-lane u64 top-10
// lists + shfl extraction merge (unchanged since r14).
__global__ __launch_bounds__(128) void scores_kernel(
    const float* __restrict__ Q, const unsigned* __restrict__ Kb,
    const int* __restrict__ lo_, const int* __restrict__ hi_,
    const int* __restrict__ bidx, unsigned long long* __restrict__ topk2) {
  int bid = blockIdx.x;
  // XCD swizzle: contiguous 256-block slab per XCD (bidx sorted).
  int sw = (bid & 7) * (M_MSG * NH * 2 / 8) + (bid >> 3);
  int m = sw >> 3;
  int h = (sw >> 1) & 3;
  int sp = sw & 1;
  int tid = threadIdx.x, lane = tid & 63, w = tid >> 6;
  int g = bidx[m];
  int lo = lo_[g], hi = hi_[g];
  int range = hi - lo;
  int n_all = (range + 63) >> 6;
  int n0 = (n_all + 1) >> 1;
  int nt = sp ? (n_all - n0) : n0;
  int start = lo + (sp ? n0 * 64 : 0);
  int end0 = lo + n0 * 64;
  int end = sp ? hi : (end0 < hi ? end0 : hi);

  __shared__ uint4 qh[KK][8];  // 6 queries x 64 dims f16-packed (768 B)
  const float4* Qv = (const float4*)Q;
  for (int i = tid; i < KK * 8; i += 128) {
    int qq = i >> 3, d8 = i & 7;
    float4 a = Qv[(size_t)(m * KK + qq) * 64 + h * 16 + d8 * 2];
    float4 b = Qv[(size_t)(m * KK + qq) * 64 + h * 16 + d8 * 2 + 1];
    uint4 p;
    p.x = pkh(a.x, a.y);
    p.y = pkh(a.z, a.w);
    p.z = pkh(b.x, b.y);
    p.w = pkh(b.z, b.w);
    qh[qq][d8] = p;
  }
  __syncthreads();

  unsigned long long lst[3][KT];
#pragma unroll
  for (int j = 0; j < 3; ++j)
#pragma unroll
    for (int k = 0; k < KT; ++k) lst[j][k] = 0ULL;

  const uint4* Kh = (const uint4*)Kb + (size_t)h * 8 * T_TOK;

#pragma unroll 1
  for (int kb = 0; kb < nt; ++kb) {
    int t = start + kb * 64 + lane;
    int tc = t < hi ? t : hi - 1;
    uint4 kw[8];
#pragma unroll
    for (int d8 = 0; d8 < 8; ++d8) kw[d8] = Kh[(size_t)d8 * T_TOK + tc];
    float acc[3];
    acc[0] = 0.f; acc[1] = 0.f; acc[2] = 0.f;
#pragma unroll
    for (int d8 = 0; d8 < 8; ++d8) {
      uint4 kv = kw[d8];
#pragma unroll
      for (int j = 0; j < 3; ++j) {
        uint4 qv = qh[w * 3 + j][d8];
        float a = acc[j];
        a = FDOT2(u2h(kv.x), u2h(qv.x), a);
        a = FDOT2(u2h(kv.y), u2h(qv.y), a);
        a = FDOT2(u2h(kv.z), u2h(qv.z), a);
        a = FDOT2(u2h(kv.w), u2h(qv.w), a);
        acc[j] = a;
      }
    }
    bool v0 = (t < end) && ((t >> 6) != m);
    unsigned nk = ~(unsigned)t;
#pragma unroll
    for (int j = 0; j < 3; ++j) {
      unsigned cc = v0 ? ordf(acc[j]) : 0u;
      unsigned long long key =
          cc ? (((unsigned long long)cc << 32) | nk) : 0ULL;
      if (key > lst[j][KT - 1]) {
        unsigned long long ins = key;
#pragma unroll
        for (int r = 0; r < KT; ++r) {
          unsigned long long cur = lst[j][r];
          unsigned long long mx = ins > cur ? ins : cur;
          unsigned long long mn = ins > cur ? cur : ins;
          lst[j][r] = mx;
          ins = mn;
        }
      }
    }
  }

  // ---- extraction merge across 64 lanes (3 queries interleaved for ILP) ----
  for (int k = 0; k < KT; ++k) {
    unsigned long long mx[3];
#pragma unroll
    for (int j = 0; j < 3; ++j) mx[j] = lst[j][0];
#pragma unroll
    for (int s_ = 1; s_ < 64; s_ <<= 1) {
#pragma unroll
      for (int j = 0; j < 3; ++j) {
        unsigned long long o = __shfl_xor(mx[j], s_, 64);
        if (o > mx[j]) mx[j] = o;
      }
    }
#pragma unroll
    for (int j = 0; j < 3; ++j) {
      if (mx[j] != 0ULL && lst[j][0] == mx[j]) {
#pragma unroll
        for (int r = 0; r < KT - 1; ++r) lst[j][r] = lst[j][r + 1];
        lst[j][KT - 1] = 0ULL;
      }
    }
    if (lane == 0) {
#pragma unroll
      for (int j = 0; j < 3; ++j) {
        int q = m * KK + w * 3 + j;
        topk2[((size_t)(q * NH + h) * 2 + sp) * KT + k] = mx[j];
      }
    }
  }
}

// ---------- 6. merge splits + softmax + gather V + Wo + scatter-add + avg ----------
__global__ __launch_bounds__(256) void finish_kernel(
    const unsigned long long* __restrict__ topk2, const float* __restrict__ V,
    const float4* __restrict__ WoP, const float* __restrict__ bo,
    const int* __restrict__ selected, float* __restrict__ out,
    float* __restrict__ out_avg) {
  int q0 = blockIdx.x * 16;
  int tid = threadIdx.x;
  __shared__ unsigned long long buf[64][2 * KT];  // 10 KB
  __shared__ float tvs[16][NH][KT];
  __shared__ int tis[16][NH][KT];
  __shared__ float wsm[16][NH * KT];
  __shared__ float att[16][256];
  // stage the 64 (q,h) pairs' split lists
  const unsigned long long* src = topk2 + (size_t)q0 * NH * 2 * KT;
  for (int i = tid; i < 64 * 2 * KT; i += 256) (&buf[0][0])[i] = src[i];
  __syncthreads();
  if (tid < 64) {
    int qq = tid >> 2, h = tid & 3;
    // two-pointer exact merge of the two sorted-desc lists + inline softmax
    int pa = 0, pb = 0;
    float e[KT];
    float m0 = 0.f, sum = 0.f;
#pragma unroll
    for (int k = 0; k < KT; ++k) {
      unsigned long long va = buf[tid][pa];
      unsigned long long vb = buf[tid][KT + pb];
      unsigned long long v;
      if (va >= vb) { v = va; ++pa; } else { v = vb; ++pb; }
      float scv;
      int t;
      if (v != 0ULL) {
        scv = unordf((unsigned)(v >> 32));
        t = (int)(~(unsigned)v);
      } else {
        scv = -1e30f;
        t = 0;
      }
      tvs[qq][h][k] = scv;
      tis[qq][h][k] = t;
      if (k == 0) m0 = scv;
      e[k] = expf(scv - m0);
      sum += e[k];
    }
    float inv = 1.f / sum;
#pragma unroll
    for (int k = 0; k < KT; ++k) wsm[qq][h * KT + k] = e[k] * inv;
  }
  __syncthreads();
  if (tid < 160) {
    int qq = tid / 10, k = tid % 10;
    out_avg[(size_t)(q0 + qq) * KT + k] =
        0.25f * (tvs[qq][0][k] + tvs[qq][1][k] + tvs[qq][2][k] + tvs[qq][3][k]);
  }
  int h = tid >> 6, d = tid & 63;
#pragma unroll 1
  for (int qq = 0; qq < 16; ++qq) {
    float a = 0.f;
#pragma unroll
    for (int k = 0; k < KT; ++k) {
      int t = tis[qq][h][k];
      a += wsm[qq][h * KT + k] * V[(size_t)t * 256 + h * 64 + d];
    }
    att[qq][tid] = a;
  }
  __syncthreads();
  float acc[16];
#pragma unroll
  for (int tt = 0; tt < 16; ++tt) acc[tt] = 0.f;
  for (int i4 = 0; i4 < 64; ++i4) {
    float4 wv = WoP[i4 * 256 + tid];  // coalesced panel load
#pragma unroll
    for (int tt = 0; tt < 16; ++tt) {
      float4 x = ((const float4*)att[tt])[i4];
      acc[tt] += x.x * wv.x + x.y * wv.y + x.z * wv.z + x.w * wv.w;
    }
  }
  float bj = bo[tid];
#pragma unroll 1
  for (int tt = 0; tt < 16; ++tt) {
    int s = selected[q0 + tt];
    out[(size_t)s * 256 + tid] += acc[tt] + bj;
  }
}

// ---------- launch ----------
extern "C" void kernel_launch(void* const* d_in, const int* in_sizes, int n_in,
                              void* d_out, int out_size, void* d_ws, size_t ws_size,
                              hipStream_t stream) {
  const float* X   = (const float*)d_in[0];
  const int*   mb  = (const int*)d_in[1];
  const int*   bidx= (const int*)d_in[2];
  const float* Wq  = (const float*)d_in[3];
  const float* bq  = (const float*)d_in[4];
  const float* Wk  = (const float*)d_in[5];
  const float* bk  = (const float*)d_in[6];
  const float* Wv  = (const float*)d_in[7];
  const float* bv  = (const float*)d_in[8];
  const float* Wi1 = (const float*)d_in[9];
  const float* bi1 = (const float*)d_in[10];
  const float* Wi2 = (const float*)d_in[11];
  const float* bi2 = (const float*)d_in[12];
  const float* Wo  = (const float*)d_in[13];
  const float* bo  = (const float*)d_in[14];

  float* out = (float*)d_out;
  float* out_avg = out + (size_t)T_TOK * D_HID;

  // K (f16 packed, 8 MB) is staged in d_out's "updated" region
  // (dead until final memcpy+scatter).
  unsigned* Kmat = (unsigned*)out;

  char* ws = (char*)d_ws;
  size_t off = 0;
  float* V = (float*)(ws + off);        off += (size_t)T_TOK * 256 * 4;   // 16.78 MB
  float* Q = (float*)(ws + off);        off += (size_t)NQ * 256 * 4;      // 1.57 MB
  float* imp = (float*)(ws + off);      off += (size_t)T_TOK * 4;
  int* selected = (int*)(ws + off);     off += (size_t)NQ * 4;
  int* lo = (int*)(ws + off);           off += 64;
  int* hi = (int*)(ws + off);           off += 64;
  unsigned long long* topk2 = (unsigned long long*)(ws + off);
  off += (size_t)NQ * NH * 2 * KT * 8;                                    // 0.98 MB
  uint4* WkH = (uint4*)(ws + off);      off += (size_t)32 * 256 * 16;     // 128 KB
  uint4* WvH = (uint4*)(ws + off);      off += (size_t)32 * 256 * 16;     // 128 KB
  float4* WqP = (float4*)(ws + off);    off += (size_t)64 * 256 * 16;     // 256 KB
  float4* WoP = (float4*)(ws + off);    off += (size_t)64 * 256 * 16;
  float4* Wi1P = (float4*)(ws + off);   off += (size_t)64 * 128 * 16;     // 128 KB
  (void)ws_size; (void)in_sizes; (void)n_in; (void)out_size;

  wpanel_kernel<<<256, 64, 0, stream>>>(Wk, Wv, Wq, Wo, Wi1, WkH, WvH, WqP,
                                        WoP, Wi1P);
  kvimp_kernel<<<1536, 256, 0, stream>>>(X, WkH, bk, WvH, bv, Wi1P, bi1, Wi2,
                                         bi2, Kmat, V, imp);
  topselq_kernel<<<M_MSG + 1, 256, 0, stream>>>(imp, mb, bidx, X, WqP, bq,
                                                selected, lo, hi, Q);
  scores_kernel<<<M_MSG * NH * 2, 128, 0, stream>>>(Q, Kmat, lo, hi, bidx,
                                                    topk2);
  hipMemcpyAsync(out, X, (size_t)T_TOK * D_HID * sizeof(float),
                 hipMemcpyDeviceToDevice, stream);
  finish_kernel<<<NQ / 16, 256, 0, stream>>>(topk2, V, WoP, bo, selected, out,
                                             out_avg);
}